// Round 5
// baseline (164.570 us; speedup 1.0000x reference)
//
#include <hip/hip_runtime.h>
#include <hip/hip_bf16.h>

typedef __bf16 bf16_t;
typedef bf16_t bf16x4 __attribute__((ext_vector_type(4)));
typedef bf16_t bf16x8 __attribute__((ext_vector_type(8)));
typedef float f32x4 __attribute__((ext_vector_type(4)));

#define AS1 __attribute__((address_space(1)))
#define AS3 __attribute__((address_space(3)))

__device__ __forceinline__ void gload_lds16(const void* g, void* l) {
    __builtin_amdgcn_global_load_lds((const AS1 void*)g, (AS3 void*)l, 16, 0, 0);
}

__device__ __forceinline__ float sigmoidf_(float v) {
    return 1.0f / (1.0f + __expf(-v));
}

// ---------------- fused f32 -> bf16 convert ----------------
__global__ __launch_bounds__(256) void k_convert3(const float* __restrict__ x,
                                                  const float* __restrict__ pr,
                                                  const float* __restrict__ ft,
                                                  bf16_t* __restrict__ dst) {
    const int n4 = 7168 * 256;
    int i = blockIdx.x * 256 + threadIdx.x;
    const int stride = gridDim.x * 256;
    for (; i < n4; i += stride) {
        float4 v;
        if (i < 1048576) v = ((const float4*)x)[i];
        else if (i < 1310720) v = ((const float4*)pr)[i - 1048576];
        else v = ((const float4*)ft)[i - 1310720];
        bf16x4 o;
        o[0] = (bf16_t)v.x; o[1] = (bf16_t)v.y; o[2] = (bf16_t)v.z; o[3] = (bf16_t)v.w;
        ((bf16x4*)dst)[i] = o;
    }
}

// ---------------- split-K reduce + final epilogue ----------------
// out[r,c] = sum_s part_bf16[s][r,c] - pa*rsums[r] - rsums[4096+c]
__global__ __launch_bounds__(256) void k_reduce4(const bf16_t* __restrict__ part,
                                                 const float* __restrict__ rsums,
                                                 const float* __restrict__ pa,
                                                 float* __restrict__ out) {
    const long idx = (long)blockIdx.x * 256 + threadIdx.x;
    const int row = (int)(idx >> 7);
    const int c8 = ((int)idx & 127) << 3;
    float sum[8] = {};
#pragma unroll
    for (int s = 0; s < 4; ++s) {
        bf16x8 v = *(const bf16x8*)(part + (long)s * 4096 * 1024 + (long)row * 1024 + c8);
#pragma unroll
        for (int j = 0; j < 8; ++j) sum[j] += (float)v[j];
    }
    const float ra = pa[0] * rsums[row];
    const f32x4 rb0 = *(const f32x4*)&rsums[4096 + c8];
    const f32x4 rb1 = *(const f32x4*)&rsums[4096 + c8 + 4];
    f32x4 o0, o1;
#pragma unroll
    for (int j = 0; j < 4; ++j) {
        o0[j] = sum[j] - ra - rb0[j];
        o1[j] = sum[4 + j] - ra - rb1[j];
    }
    f32x4* dst = (f32x4*)(out + (long)row * 1024 + c8);
    dst[0] = o0;
    dst[1] = o1;
}

// ================= 8-phase 256x256 GEMM (m201-style, plain HIP) =================
// K-loop identical to round 3/4 (verified). New: coalesced epilogues via per-wave
// 16KB LDS transpose (LDS free after final K-loop barrier; DS pipe in-order per
// wave so no extra sync). Pack acc->bf16 [128][64] with XOR ((rr>>2)&3)<<5 on the
// column byte (per-instruction grp == lane>>4 -> writes spread across 4 distinct
// 32B col-blocks, 2-way only). Stream out as 128B-per-row bf16x8 stores.
constexpr int SLICE = 16384;

template <int EPI>
__global__ __launch_bounds__(512, 2) void gemm8p(
    const bf16_t* __restrict__ A, const bf16_t* __restrict__ B,
    int NT, long ldab, long ldbb,
    bf16_t* __restrict__ O1, bf16_t* __restrict__ O1b,
    float* __restrict__ rsums,
    const float* __restrict__ pa, const float* __restrict__ pb, const float* __restrict__ pt,
    long zstride) {
    __shared__ char lds[131072];
    const int tid = threadIdx.x;
    const int wave = tid >> 6, lane = tid & 63;
    const int wm = wave >> 2, wn = wave & 3;

    // bijective XCD swizzle (nwg % 8 == 0 in all our launches)
    const int gx = gridDim.x, gy = gridDim.y;
    const int o = blockIdx.x + gx * (blockIdx.y + gy * blockIdx.z);
    const int cpx = (gx * gy * (int)gridDim.z) >> 3;
    const int v = (o & 7) * cpx + (o >> 3);
    const int bx = v % gx;
    const int rem = v / gx;
    const int by = rem % gy;
    const int bz = rem / gy;

    const long bm = (long)bx * 256, bn = (long)by * 256;
    const int kb0 = bz * NT * 64;
    const char* Ab = (const char*)A + bm * ldab;
    const char* Bb = (const char*)B + bn * ldbb;

    const int swzcb = ((lane >> 4) << 4) ^ (((lane >> 3) & 1) << 5);
    const int base_a = (wm * 128 + (lane & 15)) * 64 + swzcb;
    const int base_b = (wn * 64 + (lane & 15)) * 64 + swzcb;

    f32x4 acc[8][4] = {};
    bf16x8 bfrag[4];

    auto STAGE = [&](const char* gb, long ld, int kbyte, int ldsoff) {
#pragma unroll
        for (int j = 0; j < 2; ++j) {
            const int oo = (j * 512 + tid) << 4;
            const int r = oo >> 6;
            const int cb = (oo & 63) ^ (((oo >> 9) & 1) << 5);
            gload_lds16(gb + (long)r * ld + kbyte + cb, lds + ldsoff + (oo & ~1023));
        }
    };

#define KB(t, s) ((kb0 + (t) * 64 + (s) * 32) * 2)
#define LOFF(b, ab, s) ((((b) * 2 + (ab)) * 2 + (s)) * SLICE)
#define VM4 asm volatile("s_waitcnt vmcnt(4)" ::: "memory")
#define VM0 asm volatile("s_waitcnt vmcnt(0)" ::: "memory")

#define PHASE(Sl, QA, RB, PFSTMT, WAITSTMT)                                     \
    do {                                                                        \
        const int sA = LOFF(cur, 0, Sl);                                        \
        const int sB = LOFF(cur, 1, Sl);                                        \
        bf16x8 af[4];                                                           \
        _Pragma("unroll") for (int f = 0; f < 4; ++f)                           \
            af[f] = *(const bf16x8*)(lds + sA + base_a + (QA * 4 + f) * 1024);  \
        if (RB) {                                                               \
            _Pragma("unroll") for (int g = 0; g < 4; ++g)                       \
                bfrag[g] = *(const bf16x8*)(lds + sB + base_b + g * 1024);      \
        }                                                                       \
        PFSTMT;                                                                 \
        __builtin_amdgcn_sched_barrier(0);                                      \
        __builtin_amdgcn_s_barrier();                                           \
        __builtin_amdgcn_s_setprio(1);                                          \
        _Pragma("unroll") for (int f = 0; f < 4; ++f)                           \
            _Pragma("unroll") for (int g = 0; g < 4; ++g)                       \
                acc[QA * 4 + f][g] = __builtin_amdgcn_mfma_f32_16x16x32_bf16(   \
                    af[f], bfrag[g], acc[QA * 4 + f][g], 0, 0, 0);              \
        __builtin_amdgcn_s_setprio(0);                                          \
        __builtin_amdgcn_sched_barrier(0);                                      \
        WAITSTMT;                                                               \
        __builtin_amdgcn_s_barrier();                                           \
    } while (0)

    int cur = 0;
    STAGE(Ab, ldab, KB(0, 0), LOFF(0, 0, 0));
    STAGE(Bb, ldbb, KB(0, 0), LOFF(0, 1, 0));
    STAGE(Ab, ldab, KB(0, 1), LOFF(0, 0, 1));
    STAGE(Bb, ldbb, KB(0, 1), LOFF(0, 1, 1));
    VM4;
    __builtin_amdgcn_s_barrier();

    for (int t = 0; t < NT - 1; ++t) {
        const int nb = cur ^ 1;
        PHASE(0, 0, 1, STAGE(Ab, ldab, KB(t + 1, 0), LOFF(nb, 0, 0)), );
        PHASE(0, 1, 0, STAGE(Bb, ldbb, KB(t + 1, 0), LOFF(nb, 1, 0)), VM4);
        PHASE(1, 0, 1, STAGE(Ab, ldab, KB(t + 1, 1), LOFF(nb, 0, 1)), );
        PHASE(1, 1, 0, STAGE(Bb, ldbb, KB(t + 1, 1), LOFF(nb, 1, 1)), VM4);
        cur = nb;
    }
    PHASE(0, 0, 1, , );
    PHASE(0, 1, 0, , VM0);
    PHASE(1, 0, 1, , );
    PHASE(1, 1, 0, , );

#undef PHASE
#undef KB
#undef LOFF
#undef VM4
#undef VM0

    // ---------------- coalesced epilogues ----------------
    // C/D layout: col = lane&15, row = (lane>>4)*4 + q (m89/m91).
    const int er = (lane >> 4) << 2;
    const int ec = lane & 15;
    char* wlds = lds + wave * 16384;           // per-wave 16KB scratch
    const int lrow = lane >> 3;
    const int lcolb = (lane & 7) << 4;

    if constexpr (EPI == 3) {
#pragma unroll
        for (int fg = 0; fg < 8; ++fg)
#pragma unroll
            for (int g = 0; g < 4; ++g)
#pragma unroll
                for (int q = 0; q < 4; ++q) {
                    const int rr = fg * 16 + er + q;
                    const int cb = ((g * 16 + ec) << 1) ^ (((rr >> 2) & 3) << 5);
                    *(bf16_t*)(wlds + rr * 128 + cb) = (bf16_t)acc[fg][g][q];
                }
        asm volatile("s_waitcnt lgkmcnt(0)" ::: "memory");
        __builtin_amdgcn_sched_barrier(0);
        bf16_t* Op = O1 + bz * zstride + (bm + wm * 128) * 1024 + bn + wn * 64;
#pragma unroll
        for (int p = 0; p < 16; ++p) {
            const int row = p * 8 + lrow;
            bf16x8 vv = *(const bf16x8*)(wlds + row * 128 + (lcolb ^ (((row >> 2) & 3) << 5)));
            *(bf16x8*)((char*)(Op + (long)row * 1024) + lcolb) = vv;
        }
    } else {  // EPI == 4, fused GEMM1
        const bool isX = (bx < 16);  // block-uniform
        const float va = pa[0], vb = pb[0], vt = pt[0];
        float rs[8][4];
#pragma unroll
        for (int fg = 0; fg < 8; ++fg)
#pragma unroll
            for (int q = 0; q < 4; ++q) rs[fg][q] = 0.f;

        bf16_t* gb0 = isX ? (O1 + (bm + wm * 128) * 4096 + bn + wn * 64)
                          : (O1b + (bm - 4096 + wm * 128) * 4096 + bn + wn * 64);

#pragma unroll
        for (int half = 0; half < 2; ++half) {
#pragma unroll
            for (int fg = 0; fg < 8; ++fg)
#pragma unroll
                for (int g = 0; g < 4; ++g)
#pragma unroll
                    for (int q = 0; q < 4; ++q) {
                        const float vv = acc[fg][g][q];
                        const float s = sigmoidf_(vv);
                        const float prod = vv * s;
                        float oval;
                        if (isX) oval = half ? s : prod;
                        else     oval = half ? (vb * prod) : (vt * prod + va * s);
                        if (half == 0) rs[fg][q] += isX ? prod : vb * prod;
                        const int rr = fg * 16 + er + q;
                        const int cb = ((g * 16 + ec) << 1) ^ (((rr >> 2) & 3) << 5);
                        *(bf16_t*)(wlds + rr * 128 + cb) = (bf16_t)oval;
                    }
            asm volatile("s_waitcnt lgkmcnt(0)" ::: "memory");
            __builtin_amdgcn_sched_barrier(0);
            bf16_t* gb = gb0 + half * 2048;
#pragma unroll
            for (int p = 0; p < 16; ++p) {
                const int row = p * 8 + lrow;
                bf16x8 vv = *(const bf16x8*)(wlds + row * 128 + (lcolb ^ (((row >> 2) & 3) << 5)));
                *(bf16x8*)((char*)(gb + (long)row * 4096) + lcolb) = vv;
            }
            // half-1 ds_writes ordered behind half-0 ds_reads: DS pipe in-order per wave.
        }

        // per-row sums: 16-lane reduce, one atomic per row per wave
#pragma unroll
        for (int fg = 0; fg < 8; ++fg)
#pragma unroll
            for (int q = 0; q < 4; ++q) {
                float t = rs[fg][q];
                t += __shfl_xor(t, 1);
                t += __shfl_xor(t, 2);
                t += __shfl_xor(t, 4);
                t += __shfl_xor(t, 8);
                if (ec == 0) {
                    const long r = bm + wm * 128 + fg * 16 + er + q;
                    atomicAdd(&rsums[r], t);
                }
            }
    }
}

extern "C" void kernel_launch(void* const* d_in, const int* in_sizes, int n_in,
                              void* d_out, int out_size, void* d_ws, size_t ws_size,
                              hipStream_t stream) {
    const float* x = (const float*)d_in[0];       // [4096,1024]
    const float* feats = (const float*)d_in[1];   // [2048,1024]
    const float* protos = (const float*)d_in[2];  // [1024,1024]
    const float* pa = (const float*)d_in[3];
    const float* pb = (const float*)d_in[4];
    const float* pt = (const float*)d_in[5];
    float* out = (float*)d_out;                   // [4096,1024]

    constexpr long Bsz = 4096, D = 1024, F = 2048, P = 1024;

    bf16_t* XP = (bf16_t*)d_ws;                   // [5120 x 1024] = [x ; protos]
    bf16_t* F16 = XP + (Bsz + P) * D;             // [2048 x 1024]
    bf16_t* A2 = F16 + F * D;                     // [4096 x 4096] = [ax | sx]
    bf16_t* B2 = A2 + Bsz * 2 * F;                // [1024 x 4096] = [t*bp+a*sp | b*bp]
    float* rsums = (float*)(B2 + P * 2 * F);      // [5120] f32
    bf16_t* part = (bf16_t*)(rsums + Bsz + P);    // 4 x [4096 x 1024] bf16

    hipMemsetAsync(rsums, 0, (Bsz + P) * sizeof(float), stream);

    k_convert3<<<2048, 256, 0, stream>>>(x, protos, feats, XP);

    // fused GEMM1: [x;protos] @ feats^T  [5120 x 2048], K=1024
    gemm8p<4><<<dim3((Bsz + P) / 256, F / 256, 1), 512, 0, stream>>>(
        XP, F16, (int)(D / 64), D * 2, D * 2,
        A2, B2, rsums, pa, pb, pt, 0);

    // GEMM2 split-K=4: part[z] = A2 @ B2^T over K-slice z  [4096 x 1024] bf16
    gemm8p<3><<<dim3(Bsz / 256, P / 256, 4), 512, 0, stream>>>(
        A2, B2, (int)(2 * F / 64 / 4), 2 * F * 2, 2 * F * 2,
        part, nullptr, nullptr, nullptr, nullptr, nullptr, (long)Bsz * P);

    k_reduce4<<<2048, 256, 0, stream>>>(part, rsums, pa, out);
}

// Round 6
// 114.892 us; speedup vs baseline: 1.4324x; 1.4324x over previous
//
#include <hip/hip_runtime.h>
#include <hip/hip_bf16.h>

typedef __bf16 bf16_t;
typedef bf16_t bf16x4 __attribute__((ext_vector_type(4)));
typedef bf16_t bf16x8 __attribute__((ext_vector_type(8)));
typedef float f32x4 __attribute__((ext_vector_type(4)));

#define AS1 __attribute__((address_space(1)))
#define AS3 __attribute__((address_space(3)))

__device__ __forceinline__ void gload_lds16(const void* g, void* l) {
    __builtin_amdgcn_global_load_lds((const AS1 void*)g, (AS3 void*)l, 16, 0, 0);
}

__device__ __forceinline__ float sigmoidf_(float v) {
    return 1.0f / (1.0f + __expf(-v));
}

// ---------------- fused f32 -> bf16 convert ----------------
__global__ __launch_bounds__(256) void k_convert3(const float* __restrict__ x,
                                                  const float* __restrict__ pr,
                                                  const float* __restrict__ ft,
                                                  bf16_t* __restrict__ dst) {
    const int n4 = 7168 * 256;
    int i = blockIdx.x * 256 + threadIdx.x;
    const int stride = gridDim.x * 256;
    for (; i < n4; i += stride) {
        float4 v;
        if (i < 1048576) v = ((const float4*)x)[i];
        else if (i < 1310720) v = ((const float4*)pr)[i - 1048576];
        else v = ((const float4*)ft)[i - 1310720];
        bf16x4 o;
        o[0] = (bf16_t)v.x; o[1] = (bf16_t)v.y; o[2] = (bf16_t)v.z; o[3] = (bf16_t)v.w;
        ((bf16x4*)dst)[i] = o;
    }
}

// ---------------- split-K reduce + final epilogue (scrambled partial layout) ------
// Partial layout per z-slab (8 MB): region per GEMM2 block (bx*4+by) of 64K elems;
// within region: [wave(8)][chunk(16)][lane(64)] x 8 bf16.
// chunk = fg*2+gp; 8 elems = [gh(2)][q(4)] -> value acc[fg][gp*2+gh][q] of
// row bx*256+wm*128+fg*16+er+q, col by*256+wn*64+(gp*2+gh)*16+ec.
// out[r,c] = sum_z part[z][...] - pa*rsums[r] - rsums[4096+c]
__global__ __launch_bounds__(256) void k_reduce4(const bf16_t* __restrict__ part,
                                                 const float* __restrict__ rsums,
                                                 const float* __restrict__ pa,
                                                 float* __restrict__ out) {
    const int idx = blockIdx.x * 256 + threadIdx.x;  // [0, 524288)
    const int region = idx >> 13;                    // 64 regions (bx*4+by)
    const int widx = idx & 8191;
    const int wv = widx >> 10;
    const int chunk = (widx >> 6) & 15;
    const int ln = widx & 63;
    const int bx = region >> 2, by = region & 3;
    const int wm = wv >> 2, wn = wv & 3;
    const int fg = chunk >> 1, gp = chunk & 1;
    const int er = (ln >> 4) << 2, ec = ln & 15;
    const long off = (long)idx * 8;

    float sum[8] = {};
#pragma unroll
    for (int s = 0; s < 4; ++s) {
        bf16x8 v = *(const bf16x8*)(part + (long)s * 4194304 + off);
#pragma unroll
        for (int j = 0; j < 8; ++j) sum[j] += (float)v[j];
    }
    const int r0 = bx * 256 + wm * 128 + fg * 16 + er;
    const int c0 = by * 256 + wn * 64 + gp * 32 + ec;
    const float a = pa[0];
#pragma unroll
    for (int q = 0; q < 4; ++q) {
        const float ra = a * rsums[r0 + q];
#pragma unroll
        for (int gh = 0; gh < 2; ++gh) {
            const int c = c0 + gh * 16;
            out[(long)(r0 + q) * 1024 + c] = sum[gh * 4 + q] - ra - rsums[4096 + c];
        }
    }
}

// ================= 8-phase 256x256 GEMM (m201-style, plain HIP) =================
// K-loop identical to rounds 3/4 (verified). Epilogues:
// EPI 3: scrambled-coalesced bf16 partial (16 x bf16x8 stores, 1KB/wave-instr),
//        packed in-place from acc (no LDS, no extra live state -> no spill).
// EPI 4: round-4 scalar-store epilogue split into two half-passes (register-safe).
constexpr int SLICE = 16384;

template <int EPI>
__global__ __launch_bounds__(512, 2) void gemm8p(
    const bf16_t* __restrict__ A, const bf16_t* __restrict__ B,
    int NT, long ldab, long ldbb,
    bf16_t* __restrict__ O1, bf16_t* __restrict__ O1b,
    float* __restrict__ rsums,
    const float* __restrict__ pa, const float* __restrict__ pb, const float* __restrict__ pt,
    long zstride) {
    __shared__ char lds[131072];
    const int tid = threadIdx.x;
    const int wave = tid >> 6, lane = tid & 63;
    const int wm = wave >> 2, wn = wave & 3;

    // bijective XCD swizzle (nwg % 8 == 0 in all our launches)
    const int gx = gridDim.x, gy = gridDim.y;
    const int o = blockIdx.x + gx * (blockIdx.y + gy * blockIdx.z);
    const int cpx = (gx * gy * (int)gridDim.z) >> 3;
    const int v = (o & 7) * cpx + (o >> 3);
    const int bx = v % gx;
    const int rem = v / gx;
    const int by = rem % gy;
    const int bz = rem / gy;

    const long bm = (long)bx * 256, bn = (long)by * 256;
    const int kb0 = bz * NT * 64;
    const char* Ab = (const char*)A + bm * ldab;
    const char* Bb = (const char*)B + bn * ldbb;

    const int swzcb = ((lane >> 4) << 4) ^ (((lane >> 3) & 1) << 5);
    const int base_a = (wm * 128 + (lane & 15)) * 64 + swzcb;
    const int base_b = (wn * 64 + (lane & 15)) * 64 + swzcb;

    f32x4 acc[8][4] = {};
    bf16x8 bfrag[4];

    auto STAGE = [&](const char* gb, long ld, int kbyte, int ldsoff) {
#pragma unroll
        for (int j = 0; j < 2; ++j) {
            const int oo = (j * 512 + tid) << 4;
            const int r = oo >> 6;
            const int cb = (oo & 63) ^ (((oo >> 9) & 1) << 5);
            gload_lds16(gb + (long)r * ld + kbyte + cb, lds + ldsoff + (oo & ~1023));
        }
    };

#define KB(t, s) ((kb0 + (t) * 64 + (s) * 32) * 2)
#define LOFF(b, ab, s) ((((b) * 2 + (ab)) * 2 + (s)) * SLICE)
#define VM4 asm volatile("s_waitcnt vmcnt(4)" ::: "memory")
#define VM0 asm volatile("s_waitcnt vmcnt(0)" ::: "memory")

#define PHASE(Sl, QA, RB, PFSTMT, WAITSTMT)                                     \
    do {                                                                        \
        const int sA = LOFF(cur, 0, Sl);                                        \
        const int sB = LOFF(cur, 1, Sl);                                        \
        bf16x8 af[4];                                                           \
        _Pragma("unroll") for (int f = 0; f < 4; ++f)                           \
            af[f] = *(const bf16x8*)(lds + sA + base_a + (QA * 4 + f) * 1024);  \
        if (RB) {                                                               \
            _Pragma("unroll") for (int g = 0; g < 4; ++g)                       \
                bfrag[g] = *(const bf16x8*)(lds + sB + base_b + g * 1024);      \
        }                                                                       \
        PFSTMT;                                                                 \
        __builtin_amdgcn_sched_barrier(0);                                      \
        __builtin_amdgcn_s_barrier();                                           \
        __builtin_amdgcn_s_setprio(1);                                          \
        _Pragma("unroll") for (int f = 0; f < 4; ++f)                           \
            _Pragma("unroll") for (int g = 0; g < 4; ++g)                       \
                acc[QA * 4 + f][g] = __builtin_amdgcn_mfma_f32_16x16x32_bf16(   \
                    af[f], bfrag[g], acc[QA * 4 + f][g], 0, 0, 0);              \
        __builtin_amdgcn_s_setprio(0);                                          \
        __builtin_amdgcn_sched_barrier(0);                                      \
        WAITSTMT;                                                               \
        __builtin_amdgcn_s_barrier();                                           \
    } while (0)

    int cur = 0;
    STAGE(Ab, ldab, KB(0, 0), LOFF(0, 0, 0));
    STAGE(Bb, ldbb, KB(0, 0), LOFF(0, 1, 0));
    STAGE(Ab, ldab, KB(0, 1), LOFF(0, 0, 1));
    STAGE(Bb, ldbb, KB(0, 1), LOFF(0, 1, 1));
    VM4;
    __builtin_amdgcn_s_barrier();

    for (int t = 0; t < NT - 1; ++t) {
        const int nb = cur ^ 1;
        PHASE(0, 0, 1, STAGE(Ab, ldab, KB(t + 1, 0), LOFF(nb, 0, 0)), );
        PHASE(0, 1, 0, STAGE(Bb, ldbb, KB(t + 1, 0), LOFF(nb, 1, 0)), VM4);
        PHASE(1, 0, 1, STAGE(Ab, ldab, KB(t + 1, 1), LOFF(nb, 0, 1)), );
        PHASE(1, 1, 0, STAGE(Bb, ldbb, KB(t + 1, 1), LOFF(nb, 1, 1)), VM4);
        cur = nb;
    }
    PHASE(0, 0, 1, , );
    PHASE(0, 1, 0, , VM0);
    PHASE(1, 0, 1, , );
    PHASE(1, 1, 0, , );

#undef PHASE
#undef KB
#undef LOFF
#undef VM4
#undef VM0

    // Epilogues. C/D layout: col = lane&15, row = (lane>>4)*4 + q (m89/m91).
    const int er = (lane >> 4) << 2;
    const int ec = lane & 15;

    if constexpr (EPI == 3) {
        // scrambled-coalesced partial: region 64K elems per (bx*4+by) block
        bf16_t* Op = O1 + (long)bz * zstride + (long)(bx * 4 + by) * 65536 +
                     wave * 8192 + lane * 8;
#pragma unroll
        for (int fg = 0; fg < 8; ++fg)
#pragma unroll
            for (int gp = 0; gp < 2; ++gp) {
                bf16x8 w;
#pragma unroll
                for (int gh = 0; gh < 2; ++gh)
#pragma unroll
                    for (int q = 0; q < 4; ++q)
                        w[gh * 4 + q] = (bf16_t)acc[fg][gp * 2 + gh][q];
                *(bf16x8*)(Op + (fg * 2 + gp) * 512) = w;
            }
    } else {  // EPI == 4, fused GEMM1 (round-4 structure, two half-passes)
        const bool isX = (bx < 16);  // block-uniform
        const float va = pa[0], vb = pb[0], vt = pt[0];
        float rs[8][4];
#pragma unroll
        for (int fg = 0; fg < 8; ++fg)
#pragma unroll
            for (int q = 0; q < 4; ++q) rs[fg][q] = 0.f;

        bf16_t* gb0 = isX ? (O1 + (bm + wm * 128) * 4096 + bn + wn * 64)
                          : (O1b + (bm - 4096 + wm * 128) * 4096 + bn + wn * 64);

        // pass 1: first half (ax | theta*bp+alpha*sp) + rowsum accumulation
#pragma unroll
        for (int fg = 0; fg < 8; ++fg)
#pragma unroll
            for (int g = 0; g < 4; ++g)
#pragma unroll
                for (int q = 0; q < 4; ++q) {
                    const float vv = acc[fg][g][q];
                    const float s = sigmoidf_(vv);
                    const float prod = vv * s;
                    const float o0 = isX ? prod : (vt * prod + va * s);
                    rs[fg][q] += isX ? prod : vb * prod;
                    gb0[(long)(fg * 16 + er + q) * 4096 + g * 16 + ec] = (bf16_t)o0;
                }
        // pass 2: second half (sx | beta*bp)
#pragma unroll
        for (int fg = 0; fg < 8; ++fg)
#pragma unroll
            for (int g = 0; g < 4; ++g)
#pragma unroll
                for (int q = 0; q < 4; ++q) {
                    const float vv = acc[fg][g][q];
                    const float s = sigmoidf_(vv);
                    const float o1 = isX ? s : (vb * vv * s);
                    gb0[(long)(fg * 16 + er + q) * 4096 + 2048 + g * 16 + ec] = (bf16_t)o1;
                }

        // per-row sums: 16-lane reduce, one atomic per row per wave
#pragma unroll
        for (int fg = 0; fg < 8; ++fg)
#pragma unroll
            for (int q = 0; q < 4; ++q) {
                float t = rs[fg][q];
                t += __shfl_xor(t, 1);
                t += __shfl_xor(t, 2);
                t += __shfl_xor(t, 4);
                t += __shfl_xor(t, 8);
                if (ec == 0) {
                    const long r = bm + wm * 128 + fg * 16 + er + q;
                    atomicAdd(&rsums[r], t);
                }
            }
    }
}

extern "C" void kernel_launch(void* const* d_in, const int* in_sizes, int n_in,
                              void* d_out, int out_size, void* d_ws, size_t ws_size,
                              hipStream_t stream) {
    const float* x = (const float*)d_in[0];       // [4096,1024]
    const float* feats = (const float*)d_in[1];   // [2048,1024]
    const float* protos = (const float*)d_in[2];  // [1024,1024]
    const float* pa = (const float*)d_in[3];
    const float* pb = (const float*)d_in[4];
    const float* pt = (const float*)d_in[5];
    float* out = (float*)d_out;                   // [4096,1024]

    constexpr long Bsz = 4096, D = 1024, F = 2048, P = 1024;

    bf16_t* XP = (bf16_t*)d_ws;                   // [5120 x 1024] = [x ; protos]
    bf16_t* F16 = XP + (Bsz + P) * D;             // [2048 x 1024]
    bf16_t* A2 = F16 + F * D;                     // [4096 x 4096] = [ax | sx]
    bf16_t* B2 = A2 + Bsz * 2 * F;                // [1024 x 4096] = [t*bp+a*sp | b*bp]
    float* rsums = (float*)(B2 + P * 2 * F);      // [5120] f32
    bf16_t* part = (bf16_t*)(rsums + Bsz + P);    // 4 x [4096*1024] bf16 (scrambled)

    hipMemsetAsync(rsums, 0, (Bsz + P) * sizeof(float), stream);

    k_convert3<<<2048, 256, 0, stream>>>(x, protos, feats, XP);

    // fused GEMM1: [x;protos] @ feats^T  [5120 x 2048], K=1024
    gemm8p<4><<<dim3((Bsz + P) / 256, F / 256, 1), 512, 0, stream>>>(
        XP, F16, (int)(D / 64), D * 2, D * 2,
        A2, B2, rsums, pa, pb, pt, 0);

    // GEMM2 split-K=4: part[z] = A2 @ B2^T over K-slice z (scrambled layout)
    gemm8p<3><<<dim3(Bsz / 256, P / 256, 4), 512, 0, stream>>>(
        A2, B2, (int)(2 * F / 64 / 4), 2 * F * 2, 2 * F * 2,
        part, nullptr, nullptr, nullptr, nullptr, nullptr, (long)Bsz * P);

    k_reduce4<<<2048, 256, 0, stream>>>(part, rsums, pa, out);
}

// Round 7
// 103.405 us; speedup vs baseline: 1.5915x; 1.1111x over previous
//
#include <hip/hip_runtime.h>
#include <hip/hip_bf16.h>

typedef __bf16 bf16_t;
typedef bf16_t bf16x4 __attribute__((ext_vector_type(4)));
typedef bf16_t bf16x8 __attribute__((ext_vector_type(8)));
typedef float f32x4 __attribute__((ext_vector_type(4)));

#define AS1 __attribute__((address_space(1)))
#define AS3 __attribute__((address_space(3)))

__device__ __forceinline__ void gload_lds16(const void* g, void* l) {
    __builtin_amdgcn_global_load_lds((const AS1 void*)g, (AS3 void*)l, 16, 0, 0);
}

__device__ __forceinline__ float sigmoidf_(float v) {
    return 1.0f / (1.0f + __expf(-v));
}

// ---------------- fused f32 -> bf16 convert ----------------
__global__ __launch_bounds__(256) void k_convert3(const float* __restrict__ x,
                                                  const float* __restrict__ pr,
                                                  const float* __restrict__ ft,
                                                  bf16_t* __restrict__ dst) {
    const int n4 = 7168 * 256;
    int i = blockIdx.x * 256 + threadIdx.x;
    const int stride = gridDim.x * 256;
    for (; i < n4; i += stride) {
        float4 v;
        if (i < 1048576) v = ((const float4*)x)[i];
        else if (i < 1310720) v = ((const float4*)pr)[i - 1048576];
        else v = ((const float4*)ft)[i - 1310720];
        bf16x4 o;
        o[0] = (bf16_t)v.x; o[1] = (bf16_t)v.y; o[2] = (bf16_t)v.z; o[3] = (bf16_t)v.w;
        ((bf16x4*)dst)[i] = o;
    }
}

// ---------------- fold per-by row-sum partials ----------------
// rsums[r] = sum_{by=0..7} rsPart[by*5120 + r],  r in [0,5120)
__global__ __launch_bounds__(256) void k_foldrs(const float* __restrict__ rsPart,
                                                float* __restrict__ rsums) {
    const int r = blockIdx.x * 256 + threadIdx.x;
    float s = 0.f;
#pragma unroll
    for (int b = 0; b < 8; ++b) s += rsPart[b * 5120 + r];
    rsums[r] = s;
}

// ---------------- split-K reduce + final epilogue (scrambled partial layout) ------
// out[r,c] = sum_z part[z][...] - pa*rsums[r] - rsums[4096+c]
__global__ __launch_bounds__(256) void k_reduce4(const bf16_t* __restrict__ part,
                                                 const float* __restrict__ rsums,
                                                 const float* __restrict__ pa,
                                                 float* __restrict__ out) {
    const int idx = blockIdx.x * 256 + threadIdx.x;  // [0, 524288)
    const int region = idx >> 13;                    // 64 regions (bx*4+by)
    const int widx = idx & 8191;
    const int wv = widx >> 10;
    const int chunk = (widx >> 6) & 15;
    const int ln = widx & 63;
    const int bx = region >> 2, by = region & 3;
    const int wm = wv >> 2, wn = wv & 3;
    const int fg = chunk >> 1, gp = chunk & 1;
    const int er = (ln >> 4) << 2, ec = ln & 15;
    const long off = (long)idx * 8;

    float sum[8] = {};
#pragma unroll
    for (int s = 0; s < 4; ++s) {
        bf16x8 v = *(const bf16x8*)(part + (long)s * 4194304 + off);
#pragma unroll
        for (int j = 0; j < 8; ++j) sum[j] += (float)v[j];
    }
    const int r0 = bx * 256 + wm * 128 + fg * 16 + er;
    const int c0 = by * 256 + wn * 64 + gp * 32 + ec;
    const float a = pa[0];
#pragma unroll
    for (int q = 0; q < 4; ++q) {
        const float ra = a * rsums[r0 + q];
#pragma unroll
        for (int gh = 0; gh < 2; ++gh) {
            const int c = c0 + gh * 16;
            out[(long)(r0 + q) * 1024 + c] = sum[gh * 4 + q] - ra - rsums[4096 + c];
        }
    }
}

// ================= 8-phase 256x256 GEMM (m201-style, plain HIP) =================
// K-loop identical to rounds 3-6 (verified). Epilogues:
// EPI 3: scrambled-coalesced bf16 partial (16 x bf16x8 stores), operands A,B.
// EPI 4: SWAPPED-operand MFMA (mfma(B,A) -> lane&15 = C-row, regs = 4 consecutive
//        C-cols) => bf16x4 8B vector stores; rowsums via shfl + LDS cross-wave
//        reduce + per-by non-atomic slab write (no global atomics).
constexpr int SLICE = 16384;

template <int EPI>
__global__ __launch_bounds__(512, 2) void gemm8p(
    const bf16_t* __restrict__ A, const bf16_t* __restrict__ B,
    int NT, long ldab, long ldbb,
    bf16_t* __restrict__ O1, bf16_t* __restrict__ O1b,
    float* __restrict__ rsums,
    const float* __restrict__ pa, const float* __restrict__ pb, const float* __restrict__ pt,
    long zstride) {
    __shared__ char lds[131072];
    const int tid = threadIdx.x;
    const int wave = tid >> 6, lane = tid & 63;
    const int wm = wave >> 2, wn = wave & 3;

    // bijective XCD swizzle (nwg % 8 == 0 in all our launches)
    const int gx = gridDim.x, gy = gridDim.y;
    const int o = blockIdx.x + gx * (blockIdx.y + gy * blockIdx.z);
    const int cpx = (gx * gy * (int)gridDim.z) >> 3;
    const int v = (o & 7) * cpx + (o >> 3);
    const int bx = v % gx;
    const int rem = v / gx;
    const int by = rem % gy;
    const int bz = rem / gy;

    const long bm = (long)bx * 256, bn = (long)by * 256;
    const int kb0 = bz * NT * 64;
    const char* Ab = (const char*)A + bm * ldab;
    const char* Bb = (const char*)B + bn * ldbb;

    const int swzcb = ((lane >> 4) << 4) ^ (((lane >> 3) & 1) << 5);
    const int base_a = (wm * 128 + (lane & 15)) * 64 + swzcb;
    const int base_b = (wn * 64 + (lane & 15)) * 64 + swzcb;

    f32x4 acc[8][4] = {};
    bf16x8 bfrag[4];

    auto STAGE = [&](const char* gb, long ld, int kbyte, int ldsoff) {
#pragma unroll
        for (int j = 0; j < 2; ++j) {
            const int oo = (j * 512 + tid) << 4;
            const int r = oo >> 6;
            const int cb = (oo & 63) ^ (((oo >> 9) & 1) << 5);
            gload_lds16(gb + (long)r * ld + kbyte + cb, lds + ldsoff + (oo & ~1023));
        }
    };

#define KB(t, s) ((kb0 + (t) * 64 + (s) * 32) * 2)
#define LOFF(b, ab, s) ((((b) * 2 + (ab)) * 2 + (s)) * SLICE)
#define VM4 asm volatile("s_waitcnt vmcnt(4)" ::: "memory")
#define VM0 asm volatile("s_waitcnt vmcnt(0)" ::: "memory")

#define PHASE(Sl, QA, RB, PFSTMT, WAITSTMT)                                     \
    do {                                                                        \
        const int sA = LOFF(cur, 0, Sl);                                        \
        const int sB = LOFF(cur, 1, Sl);                                        \
        bf16x8 af[4];                                                           \
        _Pragma("unroll") for (int f = 0; f < 4; ++f)                           \
            af[f] = *(const bf16x8*)(lds + sA + base_a + (QA * 4 + f) * 1024);  \
        if (RB) {                                                               \
            _Pragma("unroll") for (int g = 0; g < 4; ++g)                       \
                bfrag[g] = *(const bf16x8*)(lds + sB + base_b + g * 1024);      \
        }                                                                       \
        PFSTMT;                                                                 \
        __builtin_amdgcn_sched_barrier(0);                                      \
        __builtin_amdgcn_s_barrier();                                           \
        __builtin_amdgcn_s_setprio(1);                                          \
        _Pragma("unroll") for (int f = 0; f < 4; ++f)                           \
            _Pragma("unroll") for (int g = 0; g < 4; ++g) {                     \
                if constexpr (EPI == 4)                                         \
                    acc[QA * 4 + f][g] = __builtin_amdgcn_mfma_f32_16x16x32_bf16( \
                        bfrag[g], af[f], acc[QA * 4 + f][g], 0, 0, 0);          \
                else                                                            \
                    acc[QA * 4 + f][g] = __builtin_amdgcn_mfma_f32_16x16x32_bf16( \
                        af[f], bfrag[g], acc[QA * 4 + f][g], 0, 0, 0);          \
            }                                                                   \
        __builtin_amdgcn_s_setprio(0);                                          \
        __builtin_amdgcn_sched_barrier(0);                                      \
        WAITSTMT;                                                               \
        __builtin_amdgcn_s_barrier();                                           \
    } while (0)

    int cur = 0;
    STAGE(Ab, ldab, KB(0, 0), LOFF(0, 0, 0));
    STAGE(Bb, ldbb, KB(0, 0), LOFF(0, 1, 0));
    STAGE(Ab, ldab, KB(0, 1), LOFF(0, 0, 1));
    STAGE(Bb, ldbb, KB(0, 1), LOFF(0, 1, 1));
    VM4;
    __builtin_amdgcn_s_barrier();

    for (int t = 0; t < NT - 1; ++t) {
        const int nb = cur ^ 1;
        PHASE(0, 0, 1, STAGE(Ab, ldab, KB(t + 1, 0), LOFF(nb, 0, 0)), );
        PHASE(0, 1, 0, STAGE(Bb, ldbb, KB(t + 1, 0), LOFF(nb, 1, 0)), VM4);
        PHASE(1, 0, 1, STAGE(Ab, ldab, KB(t + 1, 1), LOFF(nb, 0, 1)), );
        PHASE(1, 1, 0, STAGE(Bb, ldbb, KB(t + 1, 1), LOFF(nb, 1, 1)), VM4);
        cur = nb;
    }
    PHASE(0, 0, 1, , );
    PHASE(0, 1, 0, , VM0);
    PHASE(1, 0, 1, , );
    PHASE(1, 1, 0, , );

#undef PHASE
#undef KB
#undef LOFF
#undef VM4
#undef VM0

    if constexpr (EPI == 3) {
        // C/D layout (operands A,B): col = lane&15, row = (lane>>4)*4 + q.
        // scrambled-coalesced partial: region 64K elems per (bx*4+by) block
        bf16_t* Op = O1 + (long)bz * zstride + (long)(bx * 4 + by) * 65536 +
                     wave * 8192 + lane * 8;
#pragma unroll
        for (int fg = 0; fg < 8; ++fg)
#pragma unroll
            for (int gp = 0; gp < 2; ++gp) {
                bf16x8 w;
#pragma unroll
                for (int gh = 0; gh < 2; ++gh)
#pragma unroll
                    for (int q = 0; q < 4; ++q)
                        w[gh * 4 + q] = (bf16_t)acc[fg][gp * 2 + gh][q];
                *(bf16x8*)(Op + (fg * 2 + gp) * 512) = w;
            }
    } else {  // EPI == 4, swapped operands: row m = f*16 + (lane&15),
              // col n = g*16 + (lane>>4)*4 + q  -> bf16x4 vector stores
        const bool isX = (bx < 16);  // block-uniform
        const float va = pa[0], vb = pb[0], vt = pt[0];
        bf16_t* gb = isX ? O1 : O1b;
        const long rowoff = isX ? bm : bm - 4096;
        const int lm = lane & 15;
        const int ln4 = (lane >> 4) << 2;
        float rs[8];
#pragma unroll
        for (int f = 0; f < 8; ++f) rs[f] = 0.f;

#pragma unroll
        for (int f = 0; f < 8; ++f) {
            const long rbase = (rowoff + wm * 128 + f * 16 + lm) * 4096 + bn + wn * 64;
#pragma unroll
            for (int g = 0; g < 4; ++g) {
                bf16x4 w0, w1;
#pragma unroll
                for (int q = 0; q < 4; ++q) {
                    const float vv = acc[f][g][q];
                    const float s = sigmoidf_(vv);
                    const float prod = vv * s;
                    const float o0 = isX ? prod : (vt * prod + va * s);
                    const float o1 = isX ? s : (vb * prod);
                    rs[f] += isX ? prod : vb * prod;
                    w0[q] = (bf16_t)o0;
                    w1[q] = (bf16_t)o1;
                }
                const long cb = rbase + g * 16 + ln4;
                *(bf16x4*)(gb + cb) = w0;
                *(bf16x4*)(gb + cb + 2048) = w1;
            }
        }

        // rowsums: fold lane>>4 groups, stage wave partials in (now free) LDS,
        // cross-wave reduce, one non-atomic write per row into per-by slab.
        float* lds_f = (float*)lds;
#pragma unroll
        for (int f = 0; f < 8; ++f) {
            float t = rs[f];
            t += __shfl_xor(t, 16);
            t += __shfl_xor(t, 32);
            if ((lane >> 4) == 0) lds_f[wn * 256 + wm * 128 + f * 16 + lm] = t;
        }
        __syncthreads();
        if (tid < 256) {
            const float s = lds_f[tid] + lds_f[256 + tid] + lds_f[512 + tid] + lds_f[768 + tid];
            rsums[(long)by * 5120 + bm + tid] = s;  // rsums arg = rsPart base
        }
    }
}

extern "C" void kernel_launch(void* const* d_in, const int* in_sizes, int n_in,
                              void* d_out, int out_size, void* d_ws, size_t ws_size,
                              hipStream_t stream) {
    const float* x = (const float*)d_in[0];       // [4096,1024]
    const float* feats = (const float*)d_in[1];   // [2048,1024]
    const float* protos = (const float*)d_in[2];  // [1024,1024]
    const float* pa = (const float*)d_in[3];
    const float* pb = (const float*)d_in[4];
    const float* pt = (const float*)d_in[5];
    float* out = (float*)d_out;                   // [4096,1024]

    constexpr long Bsz = 4096, D = 1024, F = 2048, P = 1024;

    bf16_t* XP = (bf16_t*)d_ws;                   // [5120 x 1024] = [x ; protos]
    bf16_t* F16 = XP + (Bsz + P) * D;             // [2048 x 1024]
    bf16_t* A2 = F16 + F * D;                     // [4096 x 4096] = [ax | sx]
    bf16_t* B2 = A2 + Bsz * 2 * F;                // [1024 x 4096] = [t*bp+a*sp | b*bp]
    float* rsums = (float*)(B2 + P * 2 * F);      // [5120] f32 (folded)
    bf16_t* part = (bf16_t*)(rsums + Bsz + P);    // 4 x [4096*1024] bf16 (scrambled)
    float* rsPart = (float*)(part + 4L * Bsz * P);  // [8][5120] f32 slabs

    k_convert3<<<2048, 256, 0, stream>>>(x, protos, feats, XP);

    // fused GEMM1: [x;protos] @ feats^T  [5120 x 2048], K=1024
    gemm8p<4><<<dim3((Bsz + P) / 256, F / 256, 1), 512, 0, stream>>>(
        XP, F16, (int)(D / 64), D * 2, D * 2,
        A2, B2, rsPart, pa, pb, pt, 0);

    // fold 8 per-by row-sum slabs -> rsums[5120]
    k_foldrs<<<20, 256, 0, stream>>>(rsPart, rsums);

    // GEMM2 split-K=4: part[z] = A2 @ B2^T over K-slice z (scrambled layout)
    gemm8p<3><<<dim3(Bsz / 256, P / 256, 4), 512, 0, stream>>>(
        A2, B2, (int)(2 * F / 64 / 4), 2 * F * 2, 2 * F * 2,
        part, nullptr, nullptr, nullptr, nullptr, nullptr, (long)Bsz * P);

    k_reduce4<<<2048, 256, 0, stream>>>(part, rsums, pa, out);
}

// Round 9
// 101.444 us; speedup vs baseline: 1.6223x; 1.0193x over previous
//
#include <hip/hip_runtime.h>
#include <hip/hip_bf16.h>

typedef __bf16 bf16_t;
typedef bf16_t bf16x4 __attribute__((ext_vector_type(4)));
typedef bf16_t bf16x8 __attribute__((ext_vector_type(8)));
typedef float f32x4 __attribute__((ext_vector_type(4)));

#define AS1 __attribute__((address_space(1)))
#define AS3 __attribute__((address_space(3)))

__device__ __forceinline__ void gload_lds16(const void* g, void* l) {
    __builtin_amdgcn_global_load_lds((const AS1 void*)g, (AS3 void*)l, 16, 0, 0);
}

__device__ __forceinline__ float sigmoidf_(float v) {
    return 1.0f / (1.0f + __expf(-v));
}

// ---------------- fused f32 -> bf16 convert ----------------
__global__ __launch_bounds__(256) void k_convert3(const float* __restrict__ x,
                                                  const float* __restrict__ pr,
                                                  const float* __restrict__ ft,
                                                  bf16_t* __restrict__ dst) {
    const int n4 = 7168 * 256;
    int i = blockIdx.x * 256 + threadIdx.x;
    const int stride = gridDim.x * 256;
    for (; i < n4; i += stride) {
        float4 v;
        if (i < 1048576) v = ((const float4*)x)[i];
        else if (i < 1310720) v = ((const float4*)pr)[i - 1048576];
        else v = ((const float4*)ft)[i - 1310720];
        bf16x4 o;
        o[0] = (bf16_t)v.x; o[1] = (bf16_t)v.y; o[2] = (bf16_t)v.z; o[3] = (bf16_t)v.w;
        ((bf16x4*)dst)[i] = o;
    }
}

// ---------------- fold per-by row-sum partials ----------------
__global__ __launch_bounds__(256) void k_foldrs(const float* __restrict__ rsPart,
                                                float* __restrict__ rsums) {
    const int r = blockIdx.x * 256 + threadIdx.x;
    float s = 0.f;
#pragma unroll
    for (int b = 0; b < 8; ++b) s += rsPart[b * 5120 + r];
    rsums[r] = s;
}

// ---------------- split-K reduce + final epilogue (scrambled partial layout) ------
__global__ __launch_bounds__(256) void k_reduce4(const bf16_t* __restrict__ part,
                                                 const float* __restrict__ rsums,
                                                 const float* __restrict__ pa,
                                                 float* __restrict__ out) {
    const int idx = blockIdx.x * 256 + threadIdx.x;  // [0, 524288)
    const int region = idx >> 13;                    // 64 regions (bx*4+by)
    const int widx = idx & 8191;
    const int wv = widx >> 10;
    const int chunk = (widx >> 6) & 15;
    const int ln = widx & 63;
    const int bx = region >> 2, by = region & 3;
    const int wm = wv >> 2, wn = wv & 3;
    const int fg = chunk >> 1, gp = chunk & 1;
    const int er = (ln >> 4) << 2, ec = ln & 15;
    const long off = (long)idx * 8;

    float sum[8] = {};
#pragma unroll
    for (int s = 0; s < 4; ++s) {
        bf16x8 v = *(const bf16x8*)(part + (long)s * 4194304 + off);
#pragma unroll
        for (int j = 0; j < 8; ++j) sum[j] += (float)v[j];
    }
    const int r0 = bx * 256 + wm * 128 + fg * 16 + er;
    const int c0 = by * 256 + wn * 64 + gp * 32 + ec;
    const float a = pa[0];
#pragma unroll
    for (int q = 0; q < 4; ++q) {
        const float ra = a * rsums[r0 + q];
#pragma unroll
        for (int gh = 0; gh < 2; ++gh) {
            const int c = c0 + gh * 16;
            out[(long)(r0 + q) * 1024 + c] = sum[gh * 4 + q] - ra - rsums[4096 + c];
        }
    }
}

// ================= 8-phase 256x256 GEMM (m201-style, plain HIP) =================
// K-loop identical to rounds 3-7 (verified). Epilogues:
// EPI 3: scrambled-coalesced bf16 partial (16 x bf16x8 stores), operands A,B.
// EPI 4: swapped-op MFMA + per-frag LDS transpose -> fully coalesced 16B stores.
//        Swizzle fixed vs round 8: XOR applied to the COLUMN FIELD ONLY on both
//        write and read (carry-free involution c -> c ^ ((row&7)<<4) per row).
constexpr int SLICE = 16384;

template <int EPI>
__global__ __launch_bounds__(512, 2) void gemm8p(
    const bf16_t* __restrict__ A, const bf16_t* __restrict__ B,
    int NT, long ldab, long ldbb,
    bf16_t* __restrict__ O1, bf16_t* __restrict__ O1b,
    float* __restrict__ rsums,
    const float* __restrict__ pa, const float* __restrict__ pb, const float* __restrict__ pt,
    long zstride) {
    __shared__ char lds[131072];
    const int tid = threadIdx.x;
    const int wave = tid >> 6, lane = tid & 63;
    const int wm = wave >> 2, wn = wave & 3;

    // bijective XCD swizzle (nwg % 8 == 0 in all our launches)
    const int gx = gridDim.x, gy = gridDim.y;
    const int o = blockIdx.x + gx * (blockIdx.y + gy * blockIdx.z);
    const int cpx = (gx * gy * (int)gridDim.z) >> 3;
    const int v = (o & 7) * cpx + (o >> 3);
    const int bx = v % gx;
    const int rem = v / gx;
    const int by = rem % gy;
    const int bz = rem / gy;

    const long bm = (long)bx * 256, bn = (long)by * 256;
    const int kb0 = bz * NT * 64;
    const char* Ab = (const char*)A + bm * ldab;
    const char* Bb = (const char*)B + bn * ldbb;

    const int swzcb = ((lane >> 4) << 4) ^ (((lane >> 3) & 1) << 5);
    const int base_a = (wm * 128 + (lane & 15)) * 64 + swzcb;
    const int base_b = (wn * 64 + (lane & 15)) * 64 + swzcb;

    f32x4 acc[8][4] = {};
    bf16x8 bfrag[4];

    auto STAGE = [&](const char* gb, long ld, int kbyte, int ldsoff) {
#pragma unroll
        for (int j = 0; j < 2; ++j) {
            const int oo = (j * 512 + tid) << 4;
            const int r = oo >> 6;
            const int cb = (oo & 63) ^ (((oo >> 9) & 1) << 5);
            gload_lds16(gb + (long)r * ld + kbyte + cb, lds + ldsoff + (oo & ~1023));
        }
    };

#define KB(t, s) ((kb0 + (t) * 64 + (s) * 32) * 2)
#define LOFF(b, ab, s) ((((b) * 2 + (ab)) * 2 + (s)) * SLICE)
#define VM4 asm volatile("s_waitcnt vmcnt(4)" ::: "memory")
#define VM0 asm volatile("s_waitcnt vmcnt(0)" ::: "memory")

#define PHASE(Sl, QA, RB, PFSTMT, WAITSTMT)                                     \
    do {                                                                        \
        const int sA = LOFF(cur, 0, Sl);                                        \
        const int sB = LOFF(cur, 1, Sl);                                        \
        bf16x8 af[4];                                                           \
        _Pragma("unroll") for (int f = 0; f < 4; ++f)                           \
            af[f] = *(const bf16x8*)(lds + sA + base_a + (QA * 4 + f) * 1024);  \
        if (RB) {                                                               \
            _Pragma("unroll") for (int g = 0; g < 4; ++g)                       \
                bfrag[g] = *(const bf16x8*)(lds + sB + base_b + g * 1024);      \
        }                                                                       \
        PFSTMT;                                                                 \
        __builtin_amdgcn_sched_barrier(0);                                      \
        __builtin_amdgcn_s_barrier();                                           \
        __builtin_amdgcn_s_setprio(1);                                          \
        _Pragma("unroll") for (int f = 0; f < 4; ++f)                           \
            _Pragma("unroll") for (int g = 0; g < 4; ++g) {                     \
                if constexpr (EPI == 4)                                         \
                    acc[QA * 4 + f][g] = __builtin_amdgcn_mfma_f32_16x16x32_bf16( \
                        bfrag[g], af[f], acc[QA * 4 + f][g], 0, 0, 0);          \
                else                                                            \
                    acc[QA * 4 + f][g] = __builtin_amdgcn_mfma_f32_16x16x32_bf16( \
                        af[f], bfrag[g], acc[QA * 4 + f][g], 0, 0, 0);          \
            }                                                                   \
        __builtin_amdgcn_s_setprio(0);                                          \
        __builtin_amdgcn_sched_barrier(0);                                      \
        WAITSTMT;                                                               \
        __builtin_amdgcn_s_barrier();                                           \
    } while (0)

    int cur = 0;
    STAGE(Ab, ldab, KB(0, 0), LOFF(0, 0, 0));
    STAGE(Bb, ldbb, KB(0, 0), LOFF(0, 1, 0));
    STAGE(Ab, ldab, KB(0, 1), LOFF(0, 0, 1));
    STAGE(Bb, ldbb, KB(0, 1), LOFF(0, 1, 1));
    VM4;
    __builtin_amdgcn_s_barrier();

    for (int t = 0; t < NT - 1; ++t) {
        const int nb = cur ^ 1;
        PHASE(0, 0, 1, STAGE(Ab, ldab, KB(t + 1, 0), LOFF(nb, 0, 0)), );
        PHASE(0, 1, 0, STAGE(Bb, ldbb, KB(t + 1, 0), LOFF(nb, 1, 0)), VM4);
        PHASE(1, 0, 1, STAGE(Ab, ldab, KB(t + 1, 1), LOFF(nb, 0, 1)), );
        PHASE(1, 1, 0, STAGE(Bb, ldbb, KB(t + 1, 1), LOFF(nb, 1, 1)), VM4);
        cur = nb;
    }
    PHASE(0, 0, 1, , );
    PHASE(0, 1, 0, , VM0);
    PHASE(1, 0, 1, , );
    PHASE(1, 1, 0, , );

#undef PHASE
#undef KB
#undef LOFF
#undef VM4
#undef VM0

    if constexpr (EPI == 3) {
        // C/D layout (operands A,B): col = lane&15, row = (lane>>4)*4 + q.
        bf16_t* Op = O1 + (long)bz * zstride + (long)(bx * 4 + by) * 65536 +
                     wave * 8192 + lane * 8;
#pragma unroll
        for (int fg = 0; fg < 8; ++fg)
#pragma unroll
            for (int gp = 0; gp < 2; ++gp) {
                bf16x8 w;
#pragma unroll
                for (int gh = 0; gh < 2; ++gh)
#pragma unroll
                    for (int q = 0; q < 4; ++q)
                        w[gh * 4 + q] = (bf16_t)acc[fg][gp * 2 + gh][q];
                *(bf16x8*)(Op + (fg * 2 + gp) * 512) = w;
            }
    } else {  // EPI == 4, swapped operands: row m = mf*16+(lane&15),
              // col f = g*16+(lane>>4)*4+q. Per-frag LDS transpose -> 16B stores.
        const bool isX = (bx < 16);  // block-uniform
        const float va = pa[0], vb = pb[0], vt = pt[0];
        bf16_t* gb = isX ? O1 : O1b;
        const long rowoff = isX ? bm : bm - 4096;
        const int lm = lane & 15;
        const int ln4 = (lane >> 4) << 2;
        // scratch at +4KB so it never overlaps the cross-wave rowsum region [0,4KB)
        char* wlds = lds + 4096 + wave * 4096;   // [16m][64f] x 2B, 2 planes of 2KB
        const int wswz = (lm & 7) << 4;          // per-row column-field XOR
        float rs[8];
#pragma unroll
        for (int f = 0; f < 8; ++f) rs[f] = 0.f;

#pragma unroll
        for (int mf = 0; mf < 8; ++mf) {
            // pack both planes into LDS (8 x ds_write_b64), col-field-only XOR
#pragma unroll
            for (int g = 0; g < 4; ++g) {
                bf16x4 w0, w1;
#pragma unroll
                for (int q = 0; q < 4; ++q) {
                    const float vv = acc[mf][g][q];
                    const float s = sigmoidf_(vv);
                    const float prod = vv * s;
                    w0[q] = (bf16_t)(isX ? prod : (vt * prod + va * s));
                    w1[q] = (bf16_t)(isX ? s : (vb * prod));
                    rs[mf] += isX ? prod : vb * prod;
                }
                const int a = lm * 128 + ((g * 32 + ln4 * 2) ^ wswz);
                *(bf16x4*)(wlds + a) = w0;
                *(bf16x4*)(wlds + 2048 + a) = w1;
            }
            // coalesced read-back + 16B global stores (DS pipe in-order per wave)
#pragma unroll
            for (int rd = 0; rd < 2; ++rd) {
                const int row = rd * 8 + (lane >> 3);
                const int a = row * 128 + (((lane & 7) * 16) ^ ((row & 7) << 4));
                bf16x8 v0 = *(const bf16x8*)(wlds + a);
                bf16x8 v1 = *(const bf16x8*)(wlds + 2048 + a);
                bf16_t* dst = gb + (rowoff + wm * 128 + mf * 16 + row) * 4096 +
                              bn + wn * 64 + (lane & 7) * 8;
                *(bf16x8*)dst = v0;
                *(bf16x8*)(dst + 2048) = v1;
            }
        }

        // rowsums: fold lane>>4 groups, stage wave partials in LDS[0,4KB),
        // cross-wave reduce, one non-atomic write per row into per-by slab.
        float* lds_f = (float*)lds;
#pragma unroll
        for (int f = 0; f < 8; ++f) {
            float t = rs[f];
            t += __shfl_xor(t, 16);
            t += __shfl_xor(t, 32);
            if ((lane >> 4) == 0) lds_f[wn * 256 + wm * 128 + f * 16 + lm] = t;
        }
        __syncthreads();
        if (tid < 256) {
            const float s = lds_f[tid] + lds_f[256 + tid] + lds_f[512 + tid] + lds_f[768 + tid];
            rsums[(long)by * 5120 + bm + tid] = s;  // rsums arg = rsPart base
        }
    }
}

extern "C" void kernel_launch(void* const* d_in, const int* in_sizes, int n_in,
                              void* d_out, int out_size, void* d_ws, size_t ws_size,
                              hipStream_t stream) {
    const float* x = (const float*)d_in[0];       // [4096,1024]
    const float* feats = (const float*)d_in[1];   // [2048,1024]
    const float* protos = (const float*)d_in[2];  // [1024,1024]
    const float* pa = (const float*)d_in[3];
    const float* pb = (const float*)d_in[4];
    const float* pt = (const float*)d_in[5];
    float* out = (float*)d_out;                   // [4096,1024]

    constexpr long Bsz = 4096, D = 1024, F = 2048, P = 1024;

    bf16_t* XP = (bf16_t*)d_ws;                   // [5120 x 1024] = [x ; protos]
    bf16_t* F16 = XP + (Bsz + P) * D;             // [2048 x 1024]
    bf16_t* A2 = F16 + F * D;                     // [4096 x 4096] = [ax | sx]
    bf16_t* B2 = A2 + Bsz * 2 * F;                // [1024 x 4096] = [t*bp+a*sp | b*bp]
    float* rsums = (float*)(B2 + P * 2 * F);      // [5120] f32 (folded)
    bf16_t* part = (bf16_t*)(rsums + Bsz + P);    // 4 x [4096*1024] bf16 (scrambled)
    float* rsPart = (float*)(part + 4L * Bsz * P);  // [8][5120] f32 slabs

    k_convert3<<<2048, 256, 0, stream>>>(x, protos, feats, XP);

    // fused GEMM1: [x;protos] @ feats^T  [5120 x 2048], K=1024
    gemm8p<4><<<dim3((Bsz + P) / 256, F / 256, 1), 512, 0, stream>>>(
        XP, F16, (int)(D / 64), D * 2, D * 2,
        A2, B2, rsPart, pa, pb, pt, 0);

    // fold 8 per-by row-sum slabs -> rsums[5120]
    k_foldrs<<<20, 256, 0, stream>>>(rsPart, rsums);

    // GEMM2 split-K=4: part[z] = A2 @ B2^T over K-slice z (scrambled layout)
    gemm8p<3><<<dim3(Bsz / 256, P / 256, 4), 512, 0, stream>>>(
        A2, B2, (int)(2 * F / 64 / 4), 2 * F * 2, 2 * F * 2,
        part, nullptr, nullptr, nullptr, nullptr, nullptr, (long)Bsz * P);

    k_reduce4<<<2048, 256, 0, stream>>>(part, rsums, pa, out);
}

// Round 10
// 94.973 us; speedup vs baseline: 1.7328x; 1.0681x over previous
//
#include <hip/hip_runtime.h>
#include <hip/hip_bf16.h>

typedef __bf16 bf16_t;
typedef bf16_t bf16x4 __attribute__((ext_vector_type(4)));
typedef bf16_t bf16x8 __attribute__((ext_vector_type(8)));
typedef float f32x4 __attribute__((ext_vector_type(4)));

#define AS1 __attribute__((address_space(1)))
#define AS3 __attribute__((address_space(3)))

__device__ __forceinline__ void gload_lds16(const void* g, void* l) {
    __builtin_amdgcn_global_load_lds((const AS1 void*)g, (AS3 void*)l, 16, 0, 0);
}
__device__ __forceinline__ void gload_lds4(const void* g, void* l) {
    __builtin_amdgcn_global_load_lds((const AS1 void*)g, (AS3 void*)l, 4, 0, 0);
}

__device__ __forceinline__ float sigmoidf_(float v) {
    return 1.0f / (1.0f + __expf(-v));
}

// ---------------- fused f32 -> bf16 convert ----------------
__global__ __launch_bounds__(256) void k_convert3(const float* __restrict__ x,
                                                  const float* __restrict__ pr,
                                                  const float* __restrict__ ft,
                                                  bf16_t* __restrict__ dst) {
    const int n4 = 7168 * 256;
    int i = blockIdx.x * 256 + threadIdx.x;
    const int stride = gridDim.x * 256;
    for (; i < n4; i += stride) {
        float4 v;
        if (i < 1048576) v = ((const float4*)x)[i];
        else if (i < 1310720) v = ((const float4*)pr)[i - 1048576];
        else v = ((const float4*)ft)[i - 1310720];
        bf16x4 o;
        o[0] = (bf16_t)v.x; o[1] = (bf16_t)v.y; o[2] = (bf16_t)v.z; o[3] = (bf16_t)v.w;
        ((bf16x4*)dst)[i] = o;
    }
}

// ---------------- fold per-by row-sum partials ----------------
__global__ __launch_bounds__(256) void k_foldrs(const float* __restrict__ rsPart,
                                                float* __restrict__ rsums) {
    const int r = blockIdx.x * 256 + threadIdx.x;
    float s = 0.f;
#pragma unroll
    for (int b = 0; b < 8; ++b) s += rsPart[b * 5120 + r];
    rsums[r] = s;
}

// ---------------- split-K reduce + final epilogue (scrambled partial layout) ------
__global__ __launch_bounds__(256) void k_reduce4(const bf16_t* __restrict__ part,
                                                 const float* __restrict__ rsums,
                                                 const float* __restrict__ pa,
                                                 float* __restrict__ out) {
    const int idx = blockIdx.x * 256 + threadIdx.x;  // [0, 524288)
    const int region = idx >> 13;                    // 64 regions (bx*4+by)
    const int widx = idx & 8191;
    const int wv = widx >> 10;
    const int chunk = (widx >> 6) & 15;
    const int ln = widx & 63;
    const int bx = region >> 2, by = region & 3;
    const int wm = wv >> 2, wn = wv & 3;
    const int fg = chunk >> 1, gp = chunk & 1;
    const int er = (ln >> 4) << 2, ec = ln & 15;
    const long off = (long)idx * 8;

    float sum[8] = {};
#pragma unroll
    for (int s = 0; s < 4; ++s) {
        bf16x8 v = *(const bf16x8*)(part + (long)s * 4194304 + off);
#pragma unroll
        for (int j = 0; j < 8; ++j) sum[j] += (float)v[j];
    }
    const int r0 = bx * 256 + wm * 128 + fg * 16 + er;
    const int c0 = by * 256 + wn * 64 + gp * 32 + ec;
    const float a = pa[0];
#pragma unroll
    for (int q = 0; q < 4; ++q) {
        const float ra = a * rsums[r0 + q];
#pragma unroll
        for (int gh = 0; gh < 2; ++gh) {
            const int c = c0 + gh * 16;
            out[(long)(r0 + q) * 1024 + c] = sum[gh * 4 + q] - ra - rsums[4096 + c];
        }
    }
}

// ================= GEMM2: 8-phase 256x256 (verified K-loop, EPI3) =================
constexpr int SLICE = 16384;

__global__ __launch_bounds__(512, 2) void gemm2_8p(
    const bf16_t* __restrict__ A, const bf16_t* __restrict__ B,
    int NT, long ldab, long ldbb, bf16_t* __restrict__ O1, long zstride) {
    __shared__ char lds[131072];
    const int tid = threadIdx.x;
    const int wave = tid >> 6, lane = tid & 63;
    const int wm = wave >> 2, wn = wave & 3;

    const int gx = gridDim.x, gy = gridDim.y;
    const int o = blockIdx.x + gx * (blockIdx.y + gy * blockIdx.z);
    const int cpx = (gx * gy * (int)gridDim.z) >> 3;
    const int v = (o & 7) * cpx + (o >> 3);
    const int bx = v % gx;
    const int rem = v / gx;
    const int by = rem % gy;
    const int bz = rem / gy;

    const long bm = (long)bx * 256, bn = (long)by * 256;
    const int kb0 = bz * NT * 64;
    const char* Ab = (const char*)A + bm * ldab;
    const char* Bb = (const char*)B + bn * ldbb;

    const int swzcb = ((lane >> 4) << 4) ^ (((lane >> 3) & 1) << 5);
    const int base_a = (wm * 128 + (lane & 15)) * 64 + swzcb;
    const int base_b = (wn * 64 + (lane & 15)) * 64 + swzcb;

    f32x4 acc[8][4] = {};
    bf16x8 bfrag[4];

    auto STAGE = [&](const char* gb, long ld, int kbyte, int ldsoff) {
#pragma unroll
        for (int j = 0; j < 2; ++j) {
            const int oo = (j * 512 + tid) << 4;
            const int r = oo >> 6;
            const int cb = (oo & 63) ^ (((oo >> 9) & 1) << 5);
            gload_lds16(gb + (long)r * ld + kbyte + cb, lds + ldsoff + (oo & ~1023));
        }
    };

#define KB(t, s) ((kb0 + (t) * 64 + (s) * 32) * 2)
#define LOFF(b, ab, s) ((((b) * 2 + (ab)) * 2 + (s)) * SLICE)
#define VM4 asm volatile("s_waitcnt vmcnt(4)" ::: "memory")
#define VM0 asm volatile("s_waitcnt vmcnt(0)" ::: "memory")

#define PHASE(Sl, QA, RB, PFSTMT, WAITSTMT)                                     \
    do {                                                                        \
        const int sA = LOFF(cur, 0, Sl);                                        \
        const int sB = LOFF(cur, 1, Sl);                                        \
        bf16x8 af[4];                                                           \
        _Pragma("unroll") for (int f = 0; f < 4; ++f)                           \
            af[f] = *(const bf16x8*)(lds + sA + base_a + (QA * 4 + f) * 1024);  \
        if (RB) {                                                               \
            _Pragma("unroll") for (int g = 0; g < 4; ++g)                       \
                bfrag[g] = *(const bf16x8*)(lds + sB + base_b + g * 1024);      \
        }                                                                       \
        PFSTMT;                                                                 \
        __builtin_amdgcn_sched_barrier(0);                                      \
        __builtin_amdgcn_s_barrier();                                           \
        __builtin_amdgcn_s_setprio(1);                                          \
        _Pragma("unroll") for (int f = 0; f < 4; ++f)                           \
            _Pragma("unroll") for (int g = 0; g < 4; ++g)                       \
                acc[QA * 4 + f][g] = __builtin_amdgcn_mfma_f32_16x16x32_bf16(   \
                    af[f], bfrag[g], acc[QA * 4 + f][g], 0, 0, 0);              \
        __builtin_amdgcn_s_setprio(0);                                          \
        __builtin_amdgcn_sched_barrier(0);                                      \
        WAITSTMT;                                                               \
        __builtin_amdgcn_s_barrier();                                           \
    } while (0)

    int cur = 0;
    STAGE(Ab, ldab, KB(0, 0), LOFF(0, 0, 0));
    STAGE(Bb, ldbb, KB(0, 0), LOFF(0, 1, 0));
    STAGE(Ab, ldab, KB(0, 1), LOFF(0, 0, 1));
    STAGE(Bb, ldbb, KB(0, 1), LOFF(0, 1, 1));
    VM4;
    __builtin_amdgcn_s_barrier();

    for (int t = 0; t < NT - 1; ++t) {
        const int nb = cur ^ 1;
        PHASE(0, 0, 1, STAGE(Ab, ldab, KB(t + 1, 0), LOFF(nb, 0, 0)), );
        PHASE(0, 1, 0, STAGE(Bb, ldbb, KB(t + 1, 0), LOFF(nb, 1, 0)), VM4);
        PHASE(1, 0, 1, STAGE(Ab, ldab, KB(t + 1, 1), LOFF(nb, 0, 1)), );
        PHASE(1, 1, 0, STAGE(Bb, ldbb, KB(t + 1, 1), LOFF(nb, 1, 1)), VM4);
        cur = nb;
    }
    PHASE(0, 0, 1, , );
    PHASE(0, 1, 0, , VM0);
    PHASE(1, 0, 1, , );
    PHASE(1, 1, 0, , );

#undef PHASE
#undef KB
#undef LOFF

    // scrambled-coalesced partial write
    bf16_t* Op = O1 + (long)bz * zstride + (long)(bx * 4 + by) * 65536 +
                 wave * 8192 + lane * 8;
#pragma unroll
    for (int fg = 0; fg < 8; ++fg)
#pragma unroll
        for (int gp = 0; gp < 2; ++gp) {
            bf16x8 w;
#pragma unroll
            for (int gh = 0; gh < 2; ++gh)
#pragma unroll
                for (int q = 0; q < 4; ++q)
                    w[gh * 4 + q] = (bf16_t)acc[fg][gp * 2 + gh][q];
            *(bf16x8*)(Op + (fg * 2 + gp) * 512) = w;
        }
#undef VM4
#undef VM0
}

// ================= GEMM1: 8-phase 160x256, grid 32x8 = 256 blocks =================
// Same 4-phase/VM4 sync schedule as gemm2_8p (2 staging loads per STAGE per
// thread: A = 16B covering rows 0-127 + 4B covering rows 128-159). Swapped-op
// MFMA; per-frag LDS-transpose epilogue (col-field XOR, verified R9); per-frag
// isX (x/protos boundary at row 4096 is frag-aligned).
__global__ __launch_bounds__(512, 2) void gemm1_160(
    const bf16_t* __restrict__ A, const bf16_t* __restrict__ B,
    bf16_t* __restrict__ O1, bf16_t* __restrict__ O1b,
    float* __restrict__ rsPart,
    const float* __restrict__ pa, const float* __restrict__ pb,
    const float* __restrict__ pt) {
    __shared__ char lds[106496];  // A: 4x10240 @0, B: 4x16384 @40960
    const int tid = threadIdx.x;
    const int wave = tid >> 6, lane = tid & 63;
    const int wm = wave >> 2, wn = wave & 3;
    const int NT = 16;

    const int gx = gridDim.x, gy = gridDim.y;
    const int o = blockIdx.x + gx * blockIdx.y;
    const int cpx = (gx * gy) >> 3;
    const int v = (o & 7) * cpx + (o >> 3);
    const int bx = v % gx;
    const int by = v / gx;

    const long bm = (long)bx * 160, bn = (long)by * 256;
    const char* Ab = (const char*)A + bm * 2048;
    const char* Bb = (const char*)B + bn * 2048;

    const int swzcb = ((lane >> 4) << 4) ^ (((lane >> 3) & 1) << 5);
    const int base_a = (wm * 80 + (lane & 15)) * 64 + swzcb;
    const int base_b = (wn * 64 + (lane & 15)) * 64 + swzcb;

    f32x4 acc[5][4] = {};
    bf16x8 bfrag[4];

    // A slice = 160 rows x 64B = 10KB: one 16B load (rows 0-127) + one 4B (128-159)
    auto STAGE_A = [&](int kbyte, int ldsoff) {
        {
            const int oo = tid << 4;
            const int r = oo >> 6;
            const int cb = (oo & 63) ^ (((oo >> 9) & 1) << 5);
            gload_lds16(Ab + (long)r * 2048 + kbyte + cb, lds + ldsoff + (oo & ~1023));
        }
        {
            const int oo = 8192 + (tid << 2);
            const int r = oo >> 6;
            const int cb = (oo & 63) ^ (((oo >> 9) & 1) << 5);
            gload_lds4(Ab + (long)r * 2048 + kbyte + cb, lds + ldsoff + 8192 + wave * 256);
        }
    };
    auto STAGE_B = [&](int kbyte, int ldsoff) {
#pragma unroll
        for (int j = 0; j < 2; ++j) {
            const int oo = (j * 512 + tid) << 4;
            const int r = oo >> 6;
            const int cb = (oo & 63) ^ (((oo >> 9) & 1) << 5);
            gload_lds16(Bb + (long)r * 2048 + kbyte + cb, lds + ldsoff + (oo & ~1023));
        }
    };

#define KB1(t, s) (((t) * 64 + (s) * 32) * 2)
#define LOFF_A(b, s) (((b) * 2 + (s)) * 10240)
#define LOFF_B(b, s) (40960 + ((b) * 2 + (s)) * 16384)
#define VM4 asm volatile("s_waitcnt vmcnt(4)" ::: "memory")
#define VM0 asm volatile("s_waitcnt vmcnt(0)" ::: "memory")

#define PHASE1(Sl, FO, FN, RB, PFSTMT, WAITSTMT)                                \
    do {                                                                        \
        const int sA = LOFF_A(cur, Sl);                                         \
        const int sB = LOFF_B(cur, Sl);                                         \
        bf16x8 af[FN];                                                          \
        _Pragma("unroll") for (int f = 0; f < FN; ++f)                          \
            af[f] = *(const bf16x8*)(lds + sA + base_a + (FO + f) * 1024);      \
        if (RB) {                                                               \
            _Pragma("unroll") for (int g = 0; g < 4; ++g)                       \
                bfrag[g] = *(const bf16x8*)(lds + sB + base_b + g * 1024);      \
        }                                                                       \
        PFSTMT;                                                                 \
        __builtin_amdgcn_sched_barrier(0);                                      \
        __builtin_amdgcn_s_barrier();                                           \
        __builtin_amdgcn_s_setprio(1);                                          \
        _Pragma("unroll") for (int f = 0; f < FN; ++f)                          \
            _Pragma("unroll") for (int g = 0; g < 4; ++g)                       \
                acc[FO + f][g] = __builtin_amdgcn_mfma_f32_16x16x32_bf16(       \
                    bfrag[g], af[f], acc[FO + f][g], 0, 0, 0);                  \
        __builtin_amdgcn_s_setprio(0);                                          \
        __builtin_amdgcn_sched_barrier(0);                                      \
        WAITSTMT;                                                               \
        __builtin_amdgcn_s_barrier();                                           \
    } while (0)

    int cur = 0;
    STAGE_A(KB1(0, 0), LOFF_A(0, 0));
    STAGE_B(KB1(0, 0), LOFF_B(0, 0));
    STAGE_A(KB1(0, 1), LOFF_A(0, 1));
    STAGE_B(KB1(0, 1), LOFF_B(0, 1));
    VM4;
    __builtin_amdgcn_s_barrier();

    for (int t = 0; t < NT - 1; ++t) {
        const int nb = cur ^ 1;
        PHASE1(0, 0, 3, 1, STAGE_A(KB1(t + 1, 0), LOFF_A(nb, 0)), );
        PHASE1(0, 3, 2, 0, STAGE_B(KB1(t + 1, 0), LOFF_B(nb, 0)), VM4);
        PHASE1(1, 0, 3, 1, STAGE_A(KB1(t + 1, 1), LOFF_A(nb, 1)), );
        PHASE1(1, 3, 2, 0, STAGE_B(KB1(t + 1, 1), LOFF_B(nb, 1)), VM4);
        cur = nb;
    }
    PHASE1(0, 0, 3, 1, , );
    PHASE1(0, 3, 2, 0, , VM0);
    PHASE1(1, 0, 3, 1, , );
    PHASE1(1, 3, 2, 0, , );

#undef PHASE1
#undef KB1
#undef LOFF_A
#undef LOFF_B
#undef VM4
#undef VM0

    // Epilogue: swapped operands -> row m = mf*16+(lane&15), col = g*16+(lane>>4)*4+q
    const float va = pa[0], vb = pb[0], vt = pt[0];
    const int lm = lane & 15;
    const int ln4 = (lane >> 4) << 2;
    char* wlds = lds + 4096 + wave * 4096;   // per-wave [16][64] x 2 planes
    const int wswz = (lm & 7) << 4;
    float rs[5];
#pragma unroll
    for (int f = 0; f < 5; ++f) rs[f] = 0.f;

#pragma unroll
    for (int mf = 0; mf < 5; ++mf) {
        const long growbase = bm + wm * 80 + mf * 16;   // global row of frag start
        const bool isXf = (growbase < 4096);            // frag-aligned boundary
        bf16_t* gb = isXf ? O1 : O1b;
        const long rbase0 = isXf ? growbase : (growbase - 4096);
#pragma unroll
        for (int g = 0; g < 4; ++g) {
            bf16x4 w0, w1;
#pragma unroll
            for (int q = 0; q < 4; ++q) {
                const float vv = acc[mf][g][q];
                const float s = sigmoidf_(vv);
                const float prod = vv * s;
                w0[q] = (bf16_t)(isXf ? prod : (vt * prod + va * s));
                w1[q] = (bf16_t)(isXf ? s : (vb * prod));
                rs[mf] += isXf ? prod : vb * prod;
            }
            const int a = lm * 128 + ((g * 32 + ln4 * 2) ^ wswz);
            *(bf16x4*)(wlds + a) = w0;
            *(bf16x4*)(wlds + 2048 + a) = w1;
        }
#pragma unroll
        for (int rd = 0; rd < 2; ++rd) {
            const int row = rd * 8 + (lane >> 3);
            const int a = row * 128 + (((lane & 7) * 16) ^ ((row & 7) << 4));
            bf16x8 v0 = *(const bf16x8*)(wlds + a);
            bf16x8 v1 = *(const bf16x8*)(wlds + 2048 + a);
            bf16_t* dst = gb + (rbase0 + row) * 4096 + bn + wn * 64 + (lane & 7) * 8;
            *(bf16x8*)dst = v0;
            *(bf16x8*)(dst + 2048) = v1;
        }
    }

    // rowsums: fold lane>>4 groups, stage in LDS[0,2560), cross-wave reduce,
    // one non-atomic write per row into per-by slab.
    float* lds_f = (float*)lds;
#pragma unroll
    for (int f = 0; f < 5; ++f) {
        float t = rs[f];
        t += __shfl_xor(t, 16);
        t += __shfl_xor(t, 32);
        if ((lane >> 4) == 0) lds_f[wn * 160 + wm * 80 + f * 16 + lm] = t;
    }
    __syncthreads();
    if (tid < 160) {
        const float s = lds_f[tid] + lds_f[160 + tid] + lds_f[320 + tid] + lds_f[480 + tid];
        rsPart[(long)by * 5120 + bm + tid] = s;
    }
}

extern "C" void kernel_launch(void* const* d_in, const int* in_sizes, int n_in,
                              void* d_out, int out_size, void* d_ws, size_t ws_size,
                              hipStream_t stream) {
    const float* x = (const float*)d_in[0];       // [4096,1024]
    const float* feats = (const float*)d_in[1];   // [2048,1024]
    const float* protos = (const float*)d_in[2];  // [1024,1024]
    const float* pa = (const float*)d_in[3];
    const float* pb = (const float*)d_in[4];
    const float* pt = (const float*)d_in[5];
    float* out = (float*)d_out;                   // [4096,1024]

    constexpr long Bsz = 4096, D = 1024, F = 2048, P = 1024;

    bf16_t* XP = (bf16_t*)d_ws;                   // [5120 x 1024] = [x ; protos]
    bf16_t* F16 = XP + (Bsz + P) * D;             // [2048 x 1024]
    bf16_t* A2 = F16 + F * D;                     // [4096 x 4096] = [ax | sx]
    bf16_t* B2 = A2 + Bsz * 2 * F;                // [1024 x 4096] = [t*bp+a*sp | b*bp]
    float* rsums = (float*)(B2 + P * 2 * F);      // [5120] f32 (folded)
    bf16_t* part = (bf16_t*)(rsums + Bsz + P);    // 4 x [4096*1024] bf16 (scrambled)
    float* rsPart = (float*)(part + 4L * Bsz * P);  // [8][5120] f32 slabs

    k_convert3<<<2048, 256, 0, stream>>>(x, protos, feats, XP);

    // fused GEMM1: [x;protos] @ feats^T  [5120 x 2048], K=1024, 256 blocks
    gemm1_160<<<dim3(32, 8), 512, 0, stream>>>(XP, F16, A2, B2, rsPart, pa, pb, pt);

    // fold 8 per-by row-sum slabs -> rsums[5120]
    k_foldrs<<<20, 256, 0, stream>>>(rsPart, rsums);

    // GEMM2 split-K=4: part[z] = A2 @ B2^T over K-slice z (scrambled layout)
    gemm2_8p<<<dim3(Bsz / 256, P / 256, 4), 512, 0, stream>>>(
        A2, B2, (int)(2 * F / 64 / 4), 2 * F * 2, 2 * F * 2, part, (long)Bsz * P);

    k_reduce4<<<2048, 256, 0, stream>>>(part, rsums, pa, out);
}

// Round 11
// 94.659 us; speedup vs baseline: 1.7386x; 1.0033x over previous
//
#include <hip/hip_runtime.h>
#include <hip/hip_bf16.h>

typedef __bf16 bf16_t;
typedef bf16_t bf16x4 __attribute__((ext_vector_type(4)));
typedef bf16_t bf16x8 __attribute__((ext_vector_type(8)));
typedef float f32x4 __attribute__((ext_vector_type(4)));

#define AS1 __attribute__((address_space(1)))
#define AS3 __attribute__((address_space(3)))

__device__ __forceinline__ void gload_lds16(const void* g, void* l) {
    __builtin_amdgcn_global_load_lds((const AS1 void*)g, (AS3 void*)l, 16, 0, 0);
}
__device__ __forceinline__ void gload_lds4(const void* g, void* l) {
    __builtin_amdgcn_global_load_lds((const AS1 void*)g, (AS3 void*)l, 4, 0, 0);
}

__device__ __forceinline__ float sigmoidf_(float v) {
    return 1.0f / (1.0f + __expf(-v));
}

// ---------------- fused f32 -> bf16 convert ----------------
__global__ __launch_bounds__(256) void k_convert3(const float* __restrict__ x,
                                                  const float* __restrict__ pr,
                                                  const float* __restrict__ ft,
                                                  bf16_t* __restrict__ dst) {
    const int n4 = 7168 * 256;
    int i = blockIdx.x * 256 + threadIdx.x;
    const int stride = gridDim.x * 256;
    for (; i < n4; i += stride) {
        float4 v;
        if (i < 1048576) v = ((const float4*)x)[i];
        else if (i < 1310720) v = ((const float4*)pr)[i - 1048576];
        else v = ((const float4*)ft)[i - 1310720];
        bf16x4 o;
        o[0] = (bf16_t)v.x; o[1] = (bf16_t)v.y; o[2] = (bf16_t)v.z; o[3] = (bf16_t)v.w;
        ((bf16x4*)dst)[i] = o;
    }
}

// ---------------- fold per-by row-sum partials ----------------
__global__ __launch_bounds__(256) void k_foldrs(const float* __restrict__ rsPart,
                                                float* __restrict__ rsums) {
    const int r = blockIdx.x * 256 + threadIdx.x;
    float s = 0.f;
#pragma unroll
    for (int b = 0; b < 8; ++b) s += rsPart[b * 5120 + r];
    rsums[r] = s;
}

// ---------------- split-K reduce + final epilogue (scrambled partial layout) ------
__global__ __launch_bounds__(256) void k_reduce4(const bf16_t* __restrict__ part,
                                                 const float* __restrict__ rsums,
                                                 const float* __restrict__ pa,
                                                 float* __restrict__ out) {
    const int idx = blockIdx.x * 256 + threadIdx.x;  // [0, 524288)
    const int region = idx >> 13;                    // 64 regions (bx*4+by)
    const int widx = idx & 8191;
    const int wv = widx >> 10;
    const int chunk = (widx >> 6) & 15;
    const int ln = widx & 63;
    const int bx = region >> 2, by = region & 3;
    const int wm = wv >> 2, wn = wv & 3;
    const int fg = chunk >> 1, gp = chunk & 1;
    const int er = (ln >> 4) << 2, ec = ln & 15;
    const long off = (long)idx * 8;

    float sum[8] = {};
#pragma unroll
    for (int s = 0; s < 4; ++s) {
        bf16x8 v = *(const bf16x8*)(part + (long)s * 4194304 + off);
#pragma unroll
        for (int j = 0; j < 8; ++j) sum[j] += (float)v[j];
    }
    const int r0 = bx * 256 + wm * 128 + fg * 16 + er;
    const int c0 = by * 256 + wn * 64 + gp * 32 + ec;
    const float a = pa[0];
#pragma unroll
    for (int q = 0; q < 4; ++q) {
        const float ra = a * rsums[r0 + q];
#pragma unroll
        for (int gh = 0; gh < 2; ++gh) {
            const int c = c0 + gh * 16;
            out[(long)(r0 + q) * 1024 + c] = sum[gh * 4 + q] - ra - rsums[4096 + c];
        }
    }
}

// ================= GEMM2: merged-phase 256x256 (2 phases/K-tile) =================
// Same buffers/swizzle/vmcnt invariant as the verified 4-phase loop; each slice's
// two QA sub-phases merged into one (32-MFMA cluster, 4 barriers/K-tile not 8).
// Trace: prologue leaves 4 outstanding (s1 pair); each phase issues 4 loads (->8),
// VM4 drains the 4 oldest = exactly the pair the NEXT phase reads. Peel: VM0 at s0.
constexpr int SLICE = 16384;

__global__ __launch_bounds__(512, 2) void gemm2_8p(
    const bf16_t* __restrict__ A, const bf16_t* __restrict__ B,
    int NT, long ldab, long ldbb, bf16_t* __restrict__ O1, long zstride) {
    __shared__ char lds[131072];
    const int tid = threadIdx.x;
    const int wave = tid >> 6, lane = tid & 63;
    const int wm = wave >> 2, wn = wave & 3;

    const int gx = gridDim.x, gy = gridDim.y;
    const int o = blockIdx.x + gx * (blockIdx.y + gy * blockIdx.z);
    const int cpx = (gx * gy * (int)gridDim.z) >> 3;
    const int v = (o & 7) * cpx + (o >> 3);
    const int bx = v % gx;
    const int rem = v / gx;
    const int by = rem % gy;
    const int bz = rem / gy;

    const long bm = (long)bx * 256, bn = (long)by * 256;
    const int kb0 = bz * NT * 64;
    const char* Ab = (const char*)A + bm * ldab;
    const char* Bb = (const char*)B + bn * ldbb;

    const int swzcb = ((lane >> 4) << 4) ^ (((lane >> 3) & 1) << 5);
    const int base_a = (wm * 128 + (lane & 15)) * 64 + swzcb;
    const int base_b = (wn * 64 + (lane & 15)) * 64 + swzcb;

    f32x4 acc[8][4] = {};

    auto STAGE = [&](const char* gb, long ld, int kbyte, int ldsoff) {
#pragma unroll
        for (int j = 0; j < 2; ++j) {
            const int oo = (j * 512 + tid) << 4;
            const int r = oo >> 6;
            const int cb = (oo & 63) ^ (((oo >> 9) & 1) << 5);
            gload_lds16(gb + (long)r * ld + kbyte + cb, lds + ldsoff + (oo & ~1023));
        }
    };

#define KB(t, s) ((kb0 + (t) * 64 + (s) * 32) * 2)
#define LOFF(b, ab, s) ((((b) * 2 + (ab)) * 2 + (s)) * SLICE)
#define VM4 asm volatile("s_waitcnt vmcnt(4)" ::: "memory")
#define VM0 asm volatile("s_waitcnt vmcnt(0)" ::: "memory")

    auto PF = [&](int t1, int s, int nb) {
        STAGE(Ab, ldab, KB(t1, s), LOFF(nb, 0, s));
        STAGE(Bb, ldbb, KB(t1, s), LOFF(nb, 1, s));
    };

#define PHASE2(Sl, PFSTMT, WAITSTMT)                                            \
    do {                                                                        \
        const int sA = LOFF(cur, 0, Sl);                                        \
        const int sB = LOFF(cur, 1, Sl);                                        \
        bf16x8 af[8];                                                           \
        bf16x8 bfr[4];                                                          \
        _Pragma("unroll") for (int f = 0; f < 8; ++f)                           \
            af[f] = *(const bf16x8*)(lds + sA + base_a + f * 1024);             \
        _Pragma("unroll") for (int g = 0; g < 4; ++g)                           \
            bfr[g] = *(const bf16x8*)(lds + sB + base_b + g * 1024);            \
        PFSTMT;                                                                 \
        __builtin_amdgcn_sched_barrier(0);                                      \
        __builtin_amdgcn_s_barrier();                                           \
        __builtin_amdgcn_s_setprio(1);                                          \
        _Pragma("unroll") for (int f = 0; f < 8; ++f)                           \
            _Pragma("unroll") for (int g = 0; g < 4; ++g)                       \
                acc[f][g] = __builtin_amdgcn_mfma_f32_16x16x32_bf16(            \
                    af[f], bfr[g], acc[f][g], 0, 0, 0);                         \
        __builtin_amdgcn_s_setprio(0);                                          \
        __builtin_amdgcn_sched_barrier(0);                                      \
        WAITSTMT;                                                               \
        __builtin_amdgcn_s_barrier();                                           \
    } while (0)

    int cur = 0;
    STAGE(Ab, ldab, KB(0, 0), LOFF(0, 0, 0));
    STAGE(Bb, ldbb, KB(0, 0), LOFF(0, 1, 0));
    STAGE(Ab, ldab, KB(0, 1), LOFF(0, 0, 1));
    STAGE(Bb, ldbb, KB(0, 1), LOFF(0, 1, 1));
    VM4;
    __builtin_amdgcn_s_barrier();

    for (int t = 0; t < NT - 1; ++t) {
        const int nb = cur ^ 1;
        PHASE2(0, PF(t + 1, 0, nb), VM4);
        PHASE2(1, PF(t + 1, 1, nb), VM4);
        cur = nb;
    }
    PHASE2(0, , VM0);
    PHASE2(1, , );

#undef PHASE2
#undef KB
#undef LOFF

    // scrambled-coalesced partial write
    bf16_t* Op = O1 + (long)bz * zstride + (long)(bx * 4 + by) * 65536 +
                 wave * 8192 + lane * 8;
#pragma unroll
    for (int fg = 0; fg < 8; ++fg)
#pragma unroll
        for (int gp = 0; gp < 2; ++gp) {
            bf16x8 w;
#pragma unroll
            for (int gh = 0; gh < 2; ++gh)
#pragma unroll
                for (int q = 0; q < 4; ++q)
                    w[gh * 4 + q] = (bf16_t)acc[fg][gp * 2 + gh][q];
            *(bf16x8*)(Op + (fg * 2 + gp) * 512) = w;
        }
#undef VM4
#undef VM0
}

// ================= GEMM1: merged-phase 160x256, grid 32x8 = 256 blocks ===========
// Same vmcnt invariant (STAGE_A = 2 uniform loads/thread, STAGE_B = 2).
// Merged: 20-MFMA cluster per slice, 4 barriers/K-tile.
__global__ __launch_bounds__(512, 2) void gemm1_160(
    const bf16_t* __restrict__ A, const bf16_t* __restrict__ B,
    bf16_t* __restrict__ O1, bf16_t* __restrict__ O1b,
    float* __restrict__ rsPart,
    const float* __restrict__ pa, const float* __restrict__ pb,
    const float* __restrict__ pt) {
    __shared__ char lds[106496];  // A: 4x10240 @0, B: 4x16384 @40960
    const int tid = threadIdx.x;
    const int wave = tid >> 6, lane = tid & 63;
    const int wm = wave >> 2, wn = wave & 3;
    const int NT = 16;

    const int gx = gridDim.x, gy = gridDim.y;
    const int o = blockIdx.x + gx * blockIdx.y;
    const int cpx = (gx * gy) >> 3;
    const int v = (o & 7) * cpx + (o >> 3);
    const int bx = v % gx;
    const int by = v / gx;

    const long bm = (long)bx * 160, bn = (long)by * 256;
    const char* Ab = (const char*)A + bm * 2048;
    const char* Bb = (const char*)B + bn * 2048;

    const int swzcb = ((lane >> 4) << 4) ^ (((lane >> 3) & 1) << 5);
    const int base_a = (wm * 80 + (lane & 15)) * 64 + swzcb;
    const int base_b = (wn * 64 + (lane & 15)) * 64 + swzcb;

    f32x4 acc[5][4] = {};

    auto STAGE_A = [&](int kbyte, int ldsoff) {
        {
            const int oo = tid << 4;
            const int r = oo >> 6;
            const int cb = (oo & 63) ^ (((oo >> 9) & 1) << 5);
            gload_lds16(Ab + (long)r * 2048 + kbyte + cb, lds + ldsoff + (oo & ~1023));
        }
        {
            const int oo = 8192 + (tid << 2);
            const int r = oo >> 6;
            const int cb = (oo & 63) ^ (((oo >> 9) & 1) << 5);
            gload_lds4(Ab + (long)r * 2048 + kbyte + cb, lds + ldsoff + 8192 + wave * 256);
        }
    };
    auto STAGE_B = [&](int kbyte, int ldsoff) {
#pragma unroll
        for (int j = 0; j < 2; ++j) {
            const int oo = (j * 512 + tid) << 4;
            const int r = oo >> 6;
            const int cb = (oo & 63) ^ (((oo >> 9) & 1) << 5);
            gload_lds16(Bb + (long)r * 2048 + kbyte + cb, lds + ldsoff + (oo & ~1023));
        }
    };

#define KB1(t, s) (((t) * 64 + (s) * 32) * 2)
#define LOFF_A(b, s) (((b) * 2 + (s)) * 10240)
#define LOFF_B(b, s) (40960 + ((b) * 2 + (s)) * 16384)
#define VM4 asm volatile("s_waitcnt vmcnt(4)" ::: "memory")
#define VM0 asm volatile("s_waitcnt vmcnt(0)" ::: "memory")

    auto PF1 = [&](int t1, int s, int nb) {
        STAGE_A(KB1(t1, s), LOFF_A(nb, s));
        STAGE_B(KB1(t1, s), LOFF_B(nb, s));
    };

#define PHASE1(Sl, PFSTMT, WAITSTMT)                                            \
    do {                                                                        \
        const int sA = LOFF_A(cur, Sl);                                         \
        const int sB = LOFF_B(cur, Sl);                                         \
        bf16x8 af[5];                                                           \
        bf16x8 bfr[4];                                                          \
        _Pragma("unroll") for (int f = 0; f < 5; ++f)                           \
            af[f] = *(const bf16x8*)(lds + sA + base_a + f * 1024);             \
        _Pragma("unroll") for (int g = 0; g < 4; ++g)                           \
            bfr[g] = *(const bf16x8*)(lds + sB + base_b + g * 1024);            \
        PFSTMT;                                                                 \
        __builtin_amdgcn_sched_barrier(0);                                      \
        __builtin_amdgcn_s_barrier();                                           \
        __builtin_amdgcn_s_setprio(1);                                          \
        _Pragma("unroll") for (int f = 0; f < 5; ++f)                           \
            _Pragma("unroll") for (int g = 0; g < 4; ++g)                       \
                acc[f][g] = __builtin_amdgcn_mfma_f32_16x16x32_bf16(            \
                    bfr[g], af[f], acc[f][g], 0, 0, 0);                         \
        __builtin_amdgcn_s_setprio(0);                                          \
        __builtin_amdgcn_sched_barrier(0);                                      \
        WAITSTMT;                                                               \
        __builtin_amdgcn_s_barrier();                                           \
    } while (0)

    int cur = 0;
    STAGE_A(KB1(0, 0), LOFF_A(0, 0));
    STAGE_B(KB1(0, 0), LOFF_B(0, 0));
    STAGE_A(KB1(0, 1), LOFF_A(0, 1));
    STAGE_B(KB1(0, 1), LOFF_B(0, 1));
    VM4;
    __builtin_amdgcn_s_barrier();

    for (int t = 0; t < NT - 1; ++t) {
        const int nb = cur ^ 1;
        PHASE1(0, PF1(t + 1, 0, nb), VM4);
        PHASE1(1, PF1(t + 1, 1, nb), VM4);
        cur = nb;
    }
    PHASE1(0, , VM0);
    PHASE1(1, , );

#undef PHASE1
#undef KB1
#undef LOFF_A
#undef LOFF_B
#undef VM4
#undef VM0

    // Epilogue: swapped operands -> row m = mf*16+(lane&15), col = g*16+(lane>>4)*4+q
    const float va = pa[0], vb = pb[0], vt = pt[0];
    const int lm = lane & 15;
    const int ln4 = (lane >> 4) << 2;
    char* wlds = lds + 4096 + wave * 4096;   // per-wave [16][64] x 2 planes
    const int wswz = (lm & 7) << 4;
    float rs[5];
#pragma unroll
    for (int f = 0; f < 5; ++f) rs[f] = 0.f;

#pragma unroll
    for (int mf = 0; mf < 5; ++mf) {
        const long growbase = bm + wm * 80 + mf * 16;   // global row of frag start
        const bool isXf = (growbase < 4096);            // frag-aligned boundary
        bf16_t* gb = isXf ? O1 : O1b;
        const long rbase0 = isXf ? growbase : (growbase - 4096);
#pragma unroll
        for (int g = 0; g < 4; ++g) {
            bf16x4 w0, w1;
#pragma unroll
            for (int q = 0; q < 4; ++q) {
                const float vv = acc[mf][g][q];
                const float s = sigmoidf_(vv);
                const float prod = vv * s;
                w0[q] = (bf16_t)(isXf ? prod : (vt * prod + va * s));
                w1[q] = (bf16_t)(isXf ? s : (vb * prod));
                rs[mf] += isXf ? prod : vb * prod;
            }
            const int a = lm * 128 + ((g * 32 + ln4 * 2) ^ wswz);
            *(bf16x4*)(wlds + a) = w0;
            *(bf16x4*)(wlds + 2048 + a) = w1;
        }
#pragma unroll
        for (int rd = 0; rd < 2; ++rd) {
            const int row = rd * 8 + (lane >> 3);
            const int a = row * 128 + (((lane & 7) * 16) ^ ((row & 7) << 4));
            bf16x8 v0 = *(const bf16x8*)(wlds + a);
            bf16x8 v1 = *(const bf16x8*)(wlds + 2048 + a);
            bf16_t* dst = gb + (rbase0 + row) * 4096 + bn + wn * 64 + (lane & 7) * 8;
            *(bf16x8*)dst = v0;
            *(bf16x8*)(dst + 2048) = v1;
        }
    }

    // rowsums: fold lane>>4 groups, stage in LDS[0,2560), cross-wave reduce,
    // one non-atomic write per row into per-by slab.
    float* lds_f = (float*)lds;
#pragma unroll
    for (int f = 0; f < 5; ++f) {
        float t = rs[f];
        t += __shfl_xor(t, 16);
        t += __shfl_xor(t, 32);
        if ((lane >> 4) == 0) lds_f[wn * 160 + wm * 80 + f * 16 + lm] = t;
    }
    __syncthreads();
    if (tid < 160) {
        const float s = lds_f[tid] + lds_f[160 + tid] + lds_f[320 + tid] + lds_f[480 + tid];
        rsPart[(long)by * 5120 + bm + tid] = s;
    }
}

extern "C" void kernel_launch(void* const* d_in, const int* in_sizes, int n_in,
                              void* d_out, int out_size, void* d_ws, size_t ws_size,
                              hipStream_t stream) {
    const float* x = (const float*)d_in[0];       // [4096,1024]
    const float* feats = (const float*)d_in[1];   // [2048,1024]
    const float* protos = (const float*)d_in[2];  // [1024,1024]
    const float* pa = (const float*)d_in[3];
    const float* pb = (const float*)d_in[4];
    const float* pt = (const float*)d_in[5];
    float* out = (float*)d_out;                   // [4096,1024]

    constexpr long Bsz = 4096, D = 1024, F = 2048, P = 1024;

    bf16_t* XP = (bf16_t*)d_ws;                   // [5120 x 1024] = [x ; protos]
    bf16_t* F16 = XP + (Bsz + P) * D;             // [2048 x 1024]
    bf16_t* A2 = F16 + F * D;                     // [4096 x 4096] = [ax | sx]
    bf16_t* B2 = A2 + Bsz * 2 * F;                // [1024 x 4096] = [t*bp+a*sp | b*bp]
    float* rsums = (float*)(B2 + P * 2 * F);      // [5120] f32 (folded)
    bf16_t* part = (bf16_t*)(rsums + Bsz + P);    // 4 x [4096*1024] bf16 (scrambled)
    float* rsPart = (float*)(part + 4L * Bsz * P);  // [8][5120] f32 slabs

    k_convert3<<<2048, 256, 0, stream>>>(x, protos, feats, XP);

    // fused GEMM1: [x;protos] @ feats^T  [5120 x 2048], K=1024, 256 blocks
    gemm1_160<<<dim3(32, 8), 512, 0, stream>>>(XP, F16, A2, B2, rsPart, pa, pb, pt);

    // fold 8 per-by row-sum slabs -> rsums[5120]
    k_foldrs<<<20, 256, 0, stream>>>(rsPart, rsums);

    // GEMM2 split-K=4: part[z] = A2 @ B2^T over K-slice z (scrambled layout)
    gemm2_8p<<<dim3(Bsz / 256, P / 256, 4), 512, 0, stream>>>(
        A2, B2, (int)(2 * F / 64 / 4), 2 * F * 2, 2 * F * 2, part, (long)Bsz * P);

    k_reduce4<<<2048, 256, 0, stream>>>(part, rsums, pa, out);
}

// Round 12
// 92.514 us; speedup vs baseline: 1.7789x; 1.0232x over previous
//
#include <hip/hip_runtime.h>
#include <hip/hip_bf16.h>

typedef __bf16 bf16_t;
typedef bf16_t bf16x4 __attribute__((ext_vector_type(4)));
typedef bf16_t bf16x8 __attribute__((ext_vector_type(8)));
typedef float f32x4 __attribute__((ext_vector_type(4)));

#define AS1 __attribute__((address_space(1)))
#define AS3 __attribute__((address_space(3)))

__device__ __forceinline__ void gload_lds16(const void* g, void* l) {
    __builtin_amdgcn_global_load_lds((const AS1 void*)g, (AS3 void*)l, 16, 0, 0);
}
__device__ __forceinline__ void gload_lds4(const void* g, void* l) {
    __builtin_amdgcn_global_load_lds((const AS1 void*)g, (AS3 void*)l, 4, 0, 0);
}

__device__ __forceinline__ float sigmoidf_(float v) {
    return 1.0f / (1.0f + __expf(-v));
}

// ---------------- fused f32 -> bf16 convert ----------------
__global__ __launch_bounds__(256) void k_convert3(const float* __restrict__ x,
                                                  const float* __restrict__ pr,
                                                  const float* __restrict__ ft,
                                                  bf16_t* __restrict__ dst) {
    const int n4 = 7168 * 256;
    int i = blockIdx.x * 256 + threadIdx.x;
    const int stride = gridDim.x * 256;
    for (; i < n4; i += stride) {
        float4 v;
        if (i < 1048576) v = ((const float4*)x)[i];
        else if (i < 1310720) v = ((const float4*)pr)[i - 1048576];
        else v = ((const float4*)ft)[i - 1310720];
        bf16x4 o;
        o[0] = (bf16_t)v.x; o[1] = (bf16_t)v.y; o[2] = (bf16_t)v.z; o[3] = (bf16_t)v.w;
        ((bf16x4*)dst)[i] = o;
    }
}

// ---------------- fold per-by row-sum partials ----------------
__global__ __launch_bounds__(256) void k_foldrs(const float* __restrict__ rsPart,
                                                float* __restrict__ rsums) {
    const int r = blockIdx.x * 256 + threadIdx.x;
    float s = 0.f;
#pragma unroll
    for (int b = 0; b < 8; ++b) s += rsPart[b * 5120 + r];
    rsums[r] = s;
}

// ---------------- split-K reduce + final epilogue (scrambled partial layout) ------
__global__ __launch_bounds__(256) void k_reduce4(const bf16_t* __restrict__ part,
                                                 const float* __restrict__ rsums,
                                                 const float* __restrict__ pa,
                                                 float* __restrict__ out) {
    const int idx = blockIdx.x * 256 + threadIdx.x;  // [0, 524288)
    const int region = idx >> 13;                    // 64 regions (bx*4+by)
    const int widx = idx & 8191;
    const int wv = widx >> 10;
    const int chunk = (widx >> 6) & 15;
    const int ln = widx & 63;
    const int bx = region >> 2, by = region & 3;
    const int wm = wv >> 2, wn = wv & 3;
    const int fg = chunk >> 1, gp = chunk & 1;
    const int er = (ln >> 4) << 2, ec = ln & 15;
    const long off = (long)idx * 8;

    float sum[8] = {};
#pragma unroll
    for (int s = 0; s < 4; ++s) {
        bf16x8 v = *(const bf16x8*)(part + (long)s * 4194304 + off);
#pragma unroll
        for (int j = 0; j < 8; ++j) sum[j] += (float)v[j];
    }
    const int r0 = bx * 256 + wm * 128 + fg * 16 + er;
    const int c0 = by * 256 + wn * 64 + gp * 32 + ec;
    const float a = pa[0];
#pragma unroll
    for (int q = 0; q < 4; ++q) {
        const float ra = a * rsums[r0 + q];
#pragma unroll
        for (int gh = 0; gh < 2; ++gh) {
            const int c = c0 + gh * 16;
            out[(long)(r0 + q) * 1024 + c] = sum[gh * 4 + q] - ra - rsums[4096 + c];
        }
    }
}

// ================= GEMM2: ring-4 deep-pipelined 256x256 =================
// LDS ring of 4 slice-pairs (A 16K @ s*16384, B 16K @ 65536+s*16384) = 128 KB.
// Phase p: vmcnt-wait(drain slice p) -> barrier -> ds_read slot p%4 +
// prefetch slice p+3 into slot (p+3)%4 -> MFMA. Loads get ~3 phases to land.
// Wait trace: prologue stages slices 0-2 (12 out); steady VM8; tail VM8/VM4/VM0.
// WAR: prefetch p+3 writes slot (p-1)%4, whose reads finished before barrier p.
__global__ __launch_bounds__(512, 2) void gemm2_8p(
    const bf16_t* __restrict__ A, const bf16_t* __restrict__ B,
    int NT, long ldab, long ldbb, bf16_t* __restrict__ O1, long zstride) {
    __shared__ char lds[131072];
    const int tid = threadIdx.x;
    const int wave = tid >> 6, lane = tid & 63;
    const int wm = wave >> 2, wn = wave & 3;

    const int gx = gridDim.x, gy = gridDim.y;
    const int o = blockIdx.x + gx * (blockIdx.y + gy * blockIdx.z);
    const int cpx = (gx * gy * (int)gridDim.z) >> 3;
    const int v = (o & 7) * cpx + (o >> 3);
    const int bx = v % gx;
    const int rem = v / gx;
    const int by = rem % gy;
    const int bz = rem / gy;

    const long bm = (long)bx * 256, bn = (long)by * 256;
    const int kb0 = bz * NT * 64;
    const char* Ab = (const char*)A + bm * ldab;
    const char* Bb = (const char*)B + bn * ldbb;

    const int swzcb = ((lane >> 4) << 4) ^ (((lane >> 3) & 1) << 5);
    const int base_a = (wm * 128 + (lane & 15)) * 64 + swzcb;
    const int base_b = (wn * 64 + (lane & 15)) * 64 + swzcb;

    f32x4 acc[8][4] = {};

    auto STAGE = [&](const char* gb, long ld, int kbyte, int ldsoff) {
#pragma unroll
        for (int j = 0; j < 2; ++j) {
            const int oo = (j * 512 + tid) << 4;
            const int r = oo >> 6;
            const int cb = (oo & 63) ^ (((oo >> 9) & 1) << 5);
            gload_lds16(gb + (long)r * ld + kbyte + cb, lds + ldsoff + (oo & ~1023));
        }
    };

#define VM8 asm volatile("s_waitcnt vmcnt(8)" ::: "memory")
#define VM4 asm volatile("s_waitcnt vmcnt(4)" ::: "memory")
#define VM0 asm volatile("s_waitcnt vmcnt(0)" ::: "memory")

    auto PFETCH = [&](int pf) {  // stage slice pf into slot pf&3
        const int kbyte = (kb0 + pf * 32) * 2;
        const int ps = pf & 3;
        STAGE(Ab, ldab, kbyte, ps * 16384);
        STAGE(Bb, ldbb, kbyte, 65536 + ps * 16384);
    };

#define PHASE2(p, WAITSTMT, DOPF)                                               \
    do {                                                                        \
        WAITSTMT;                                                               \
        __builtin_amdgcn_s_barrier();                                           \
        const int slot = (p) & 3;                                               \
        const char* sA = lds + slot * 16384;                                    \
        const char* sB = lds + 65536 + slot * 16384;                            \
        bf16x8 af[8];                                                           \
        bf16x8 bfr[4];                                                          \
        _Pragma("unroll") for (int f = 0; f < 8; ++f)                           \
            af[f] = *(const bf16x8*)(sA + base_a + f * 1024);                   \
        _Pragma("unroll") for (int g = 0; g < 4; ++g)                           \
            bfr[g] = *(const bf16x8*)(sB + base_b + g * 1024);                  \
        if (DOPF) PFETCH((p) + 3);                                              \
        __builtin_amdgcn_sched_barrier(0);                                      \
        __builtin_amdgcn_s_setprio(1);                                          \
        _Pragma("unroll") for (int f = 0; f < 8; ++f)                           \
            _Pragma("unroll") for (int g = 0; g < 4; ++g)                       \
                acc[f][g] = __builtin_amdgcn_mfma_f32_16x16x32_bf16(            \
                    af[f], bfr[g], acc[f][g], 0, 0, 0);                         \
        __builtin_amdgcn_s_setprio(0);                                          \
        __builtin_amdgcn_sched_barrier(0);                                      \
    } while (0)

    const int NP = NT * 2;
    PFETCH(0);
    PFETCH(1);
    PFETCH(2);

    for (int p = 0; p < NP - 3; ++p) PHASE2(p, VM8, 1);
    PHASE2(NP - 3, VM8, 0);
    PHASE2(NP - 2, VM4, 0);
    PHASE2(NP - 1, VM0, 0);

#undef PHASE2
#undef VM8
#undef VM4
#undef VM0

    // scrambled-coalesced partial write (registers only, no LDS -> no barrier)
    bf16_t* Op = O1 + (long)bz * zstride + (long)(bx * 4 + by) * 65536 +
                 wave * 8192 + lane * 8;
#pragma unroll
    for (int fg = 0; fg < 8; ++fg)
#pragma unroll
        for (int gp = 0; gp < 2; ++gp) {
            bf16x8 w;
#pragma unroll
            for (int gh = 0; gh < 2; ++gh)
#pragma unroll
                for (int q = 0; q < 4; ++q)
                    w[gh * 4 + q] = (bf16_t)acc[fg][gp * 2 + gh][q];
            *(bf16x8*)(Op + (fg * 2 + gp) * 512) = w;
        }
}

// ================= GEMM1: ring-4 deep-pipelined 160x256, 256 blocks ===========
// Ring: A 10K @ s*10240 (40K), B 16K @ 40960+s*16384 (64K) = 104 KB + tail.
// Same wait trace as gemm2 (4 loads/wave/phase). Swapped-op MFMA (20/phase).
__global__ __launch_bounds__(512, 2) void gemm1_160(
    const bf16_t* __restrict__ A, const bf16_t* __restrict__ B,
    bf16_t* __restrict__ O1, bf16_t* __restrict__ O1b,
    float* __restrict__ rsPart,
    const float* __restrict__ pa, const float* __restrict__ pb,
    const float* __restrict__ pt) {
    __shared__ char lds[106496];
    const int tid = threadIdx.x;
    const int wave = tid >> 6, lane = tid & 63;
    const int wm = wave >> 2, wn = wave & 3;
    const int NT = 16;

    const int gx = gridDim.x, gy = gridDim.y;
    const int o = blockIdx.x + gx * blockIdx.y;
    const int cpx = (gx * gy) >> 3;
    const int v = (o & 7) * cpx + (o >> 3);
    const int bx = v % gx;
    const int by = v / gx;

    const long bm = (long)bx * 160, bn = (long)by * 256;
    const char* Ab = (const char*)A + bm * 2048;
    const char* Bb = (const char*)B + bn * 2048;

    const int swzcb = ((lane >> 4) << 4) ^ (((lane >> 3) & 1) << 5);
    const int base_a = (wm * 80 + (lane & 15)) * 64 + swzcb;
    const int base_b = (wn * 64 + (lane & 15)) * 64 + swzcb;

    f32x4 acc[5][4] = {};

    auto STAGE_A = [&](int kbyte, int ldsoff) {
        {
            const int oo = tid << 4;
            const int r = oo >> 6;
            const int cb = (oo & 63) ^ (((oo >> 9) & 1) << 5);
            gload_lds16(Ab + (long)r * 2048 + kbyte + cb, lds + ldsoff + (oo & ~1023));
        }
        {
            const int oo = 8192 + (tid << 2);
            const int r = oo >> 6;
            const int cb = (oo & 63) ^ (((oo >> 9) & 1) << 5);
            gload_lds4(Ab + (long)r * 2048 + kbyte + cb, lds + ldsoff + 8192 + wave * 256);
        }
    };
    auto STAGE_B = [&](int kbyte, int ldsoff) {
#pragma unroll
        for (int j = 0; j < 2; ++j) {
            const int oo = (j * 512 + tid) << 4;
            const int r = oo >> 6;
            const int cb = (oo & 63) ^ (((oo >> 9) & 1) << 5);
            gload_lds16(Bb + (long)r * 2048 + kbyte + cb, lds + ldsoff + (oo & ~1023));
        }
    };

#define VM8 asm volatile("s_waitcnt vmcnt(8)" ::: "memory")
#define VM4 asm volatile("s_waitcnt vmcnt(4)" ::: "memory")
#define VM0 asm volatile("s_waitcnt vmcnt(0)" ::: "memory")

    auto PFETCH = [&](int pf) {
        const int kbyte = pf * 64;
        const int ps = pf & 3;
        STAGE_A(kbyte, ps * 10240);
        STAGE_B(kbyte, 40960 + ps * 16384);
    };

#define PHASE1(p, WAITSTMT, DOPF)                                               \
    do {                                                                        \
        WAITSTMT;                                                               \
        __builtin_amdgcn_s_barrier();                                           \
        const int slot = (p) & 3;                                               \
        const char* sA = lds + slot * 10240;                                    \
        const char* sB = lds + 40960 + slot * 16384;                            \
        bf16x8 af[5];                                                           \
        bf16x8 bfr[4];                                                          \
        _Pragma("unroll") for (int f = 0; f < 5; ++f)                           \
            af[f] = *(const bf16x8*)(sA + base_a + f * 1024);                   \
        _Pragma("unroll") for (int g = 0; g < 4; ++g)                           \
            bfr[g] = *(const bf16x8*)(sB + base_b + g * 1024);                  \
        if (DOPF) PFETCH((p) + 3);                                              \
        __builtin_amdgcn_sched_barrier(0);                                      \
        __builtin_amdgcn_s_setprio(1);                                          \
        _Pragma("unroll") for (int f = 0; f < 5; ++f)                           \
            _Pragma("unroll") for (int g = 0; g < 4; ++g)                       \
                acc[f][g] = __builtin_amdgcn_mfma_f32_16x16x32_bf16(            \
                    bfr[g], af[f], acc[f][g], 0, 0, 0);                         \
        __builtin_amdgcn_s_setprio(0);                                          \
        __builtin_amdgcn_sched_barrier(0);                                      \
    } while (0)

    const int NP = NT * 2;
    PFETCH(0);
    PFETCH(1);
    PFETCH(2);

    for (int p = 0; p < NP - 3; ++p) PHASE1(p, VM8, 1);
    PHASE1(NP - 3, VM8, 0);
    PHASE1(NP - 2, VM4, 0);
    PHASE1(NP - 1, VM0, 0);

#undef PHASE1
#undef VM8
#undef VM4
#undef VM0

    // epilogue scratch overlaps ring slot 3 -> must sync all waves first
    __syncthreads();

    // Epilogue: swapped operands -> row m = mf*16+(lane&15), col = g*16+(lane>>4)*4+q
    const float va = pa[0], vb = pb[0], vt = pt[0];
    const int lm = lane & 15;
    const int ln4 = (lane >> 4) << 2;
    char* wlds = lds + 4096 + wave * 4096;   // per-wave [16][64] x 2 planes
    const int wswz = (lm & 7) << 4;
    float rs[5];
#pragma unroll
    for (int f = 0; f < 5; ++f) rs[f] = 0.f;

#pragma unroll
    for (int mf = 0; mf < 5; ++mf) {
        const long growbase = bm + wm * 80 + mf * 16;   // global row of frag start
        const bool isXf = (growbase < 4096);            // frag-aligned boundary
        bf16_t* gb = isXf ? O1 : O1b;
        const long rbase0 = isXf ? growbase : (growbase - 4096);
#pragma unroll
        for (int g = 0; g < 4; ++g) {
            bf16x4 w0, w1;
#pragma unroll
            for (int q = 0; q < 4; ++q) {
                const float vv = acc[mf][g][q];
                const float s = sigmoidf_(vv);
                const float prod = vv * s;
                w0[q] = (bf16_t)(isXf ? prod : (vt * prod + va * s));
                w1[q] = (bf16_t)(isXf ? s : (vb * prod));
                rs[mf] += isXf ? prod : vb * prod;
            }
            const int a = lm * 128 + ((g * 32 + ln4 * 2) ^ wswz);
            *(bf16x4*)(wlds + a) = w0;
            *(bf16x4*)(wlds + 2048 + a) = w1;
        }
#pragma unroll
        for (int rd = 0; rd < 2; ++rd) {
            const int row = rd * 8 + (lane >> 3);
            const int a = row * 128 + (((lane & 7) * 16) ^ ((row & 7) << 4));
            bf16x8 v0 = *(const bf16x8*)(wlds + a);
            bf16x8 v1 = *(const bf16x8*)(wlds + 2048 + a);
            bf16_t* dst = gb + (rbase0 + row) * 4096 + bn + wn * 64 + (lane & 7) * 8;
            *(bf16x8*)dst = v0;
            *(bf16x8*)(dst + 2048) = v1;
        }
    }

    // rowsums: fold lane>>4 groups, stage in LDS[0,2560), cross-wave reduce,
    // one non-atomic write per row into per-by slab.
    float* lds_f = (float*)lds;
#pragma unroll
    for (int f = 0; f < 5; ++f) {
        float t = rs[f];
        t += __shfl_xor(t, 16);
        t += __shfl_xor(t, 32);
        if ((lane >> 4) == 0) lds_f[wn * 160 + wm * 80 + f * 16 + lm] = t;
    }
    __syncthreads();
    if (tid < 160) {
        const float s = lds_f[tid] + lds_f[160 + tid] + lds_f[320 + tid] + lds_f[480 + tid];
        rsPart[(long)by * 5120 + bm + tid] = s;
    }
}

extern "C" void kernel_launch(void* const* d_in, const int* in_sizes, int n_in,
                              void* d_out, int out_size, void* d_ws, size_t ws_size,
                              hipStream_t stream) {
    const float* x = (const float*)d_in[0];       // [4096,1024]
    const float* feats = (const float*)d_in[1];   // [2048,1024]
    const float* protos = (const float*)d_in[2];  // [1024,1024]
    const float* pa = (const float*)d_in[3];
    const float* pb = (const float*)d_in[4];
    const float* pt = (const float*)d_in[5];
    float* out = (float*)d_out;                   // [4096,1024]

    constexpr long Bsz = 4096, D = 1024, F = 2048, P = 1024;

    bf16_t* XP = (bf16_t*)d_ws;                   // [5120 x 1024] = [x ; protos]
    bf16_t* F16 = XP + (Bsz + P) * D;             // [2048 x 1024]
    bf16_t* A2 = F16 + F * D;                     // [4096 x 4096] = [ax | sx]
    bf16_t* B2 = A2 + Bsz * 2 * F;                // [1024 x 4096] = [t*bp+a*sp | b*bp]
    float* rsums = (float*)(B2 + P * 2 * F);      // [5120] f32 (folded)
    bf16_t* part = (bf16_t*)(rsums + Bsz + P);    // 4 x [4096*1024] bf16 (scrambled)
    float* rsPart = (float*)(part + 4L * Bsz * P);  // [8][5120] f32 slabs

    k_convert3<<<2048, 256, 0, stream>>>(x, protos, feats, XP);

    // fused GEMM1: [x;protos] @ feats^T  [5120 x 2048], K=1024, 256 blocks
    gemm1_160<<<dim3(32, 8), 512, 0, stream>>>(XP, F16, A2, B2, rsPart, pa, pb, pt);

    // fold 8 per-by row-sum slabs -> rsums[5120]
    k_foldrs<<<20, 256, 0, stream>>>(rsPart, rsums);

    // GEMM2 split-K=4: part[z] = A2 @ B2^T over K-slice z (scrambled layout)
    gemm2_8p<<<dim3(Bsz / 256, P / 256, 4), 512, 0, stream>>>(
        A2, B2, (int)(2 * F / 64 / 4), 2 * F * 2, 2 * F * 2, part, (long)Bsz * P);

    k_reduce4<<<2048, 256, 0, stream>>>(part, rsums, pa, out);
}